// Round 6
// baseline (188.937 us; speedup 1.0000x reference)
//
#include <hip/hip_runtime.h>
#include <math.h>

// Shapes (fixed): Na=32, La=32, B=64, Lb=32, Din=H=768.

typedef __attribute__((ext_vector_type(8))) short bfrag8;   // 8 bf16 in 4 VGPRs
typedef __attribute__((ext_vector_type(4))) float f32x4;

__device__ __forceinline__ unsigned short f2bf(float x) {
  union { float f; unsigned u; } v; v.f = x;
  unsigned r = v.u + 0x7fffu + ((v.u >> 16) & 1u);
  return (unsigned short)(r >> 16);
}

// DPP-based add-reduction over 16-lane rows (VALU pipe; avoids ds_swizzle latency).
template <int CTRL>
__device__ __forceinline__ float dpp_add(float x) {
  union { float f; int i; } a, b;
  a.f = x;
  b.i = __builtin_amdgcn_update_dpp(0, a.i, CTRL, 0xf, 0xf, true);
  return x + b.f;
}
// full sum over the 16 lanes of a DPP row (cg dimension), result in all 16 lanes
__device__ __forceinline__ float sum16(float x) {
  x = dpp_add<0xB1>(x);    // quad_perm [1,0,3,2]  : xor 1
  x = dpp_add<0x4E>(x);    // quad_perm [2,3,0,1]  : xor 2
  x = dpp_add<0x124>(x);   // row_ror:4
  x = dpp_add<0x128>(x);   // row_ror:8
  return x;
}

// ---------------- prep: casts (3 tensors) + zero norm buffer + 4 weight transposes -------------
__global__ __launch_bounds__(256) void prep_kernel(
    const float* __restrict__ a0, const float* __restrict__ a1, const float* __restrict__ a2,
    unsigned short* __restrict__ o0, unsigned short* __restrict__ o1, unsigned short* __restrict__ o2,
    float* __restrict__ nrm,
    const float* __restrict__ W0, const float* __restrict__ W1,
    const float* __restrict__ W2, const float* __restrict__ W3,
    unsigned short* __restrict__ T0, unsigned short* __restrict__ T1,
    unsigned short* __restrict__ T2, unsigned short* __restrict__ T3) {
  __shared__ float t[32][33];
  int bx = blockIdx.x;
  if (bx < 2331) {
    if (bx < 2328) {
      const float* in; unsigned short* out; int i, n4;
      if (bx < 768)       { in = a0; out = o0; i = bx * 256 + threadIdx.x;          n4 = 196608; }
      else if (bx < 2304) { in = a1; out = o1; i = (bx - 768) * 256 + threadIdx.x;  n4 = 393216; }
      else                { in = a2; out = o2; i = (bx - 2304) * 256 + threadIdx.x; n4 = 6144; }
      if (i >= n4) return;
      float4 f = ((const float4*)in)[i];
      ushort4 o;
      o.x = f2bf(f.x); o.y = f2bf(f.y); o.z = f2bf(f.z); o.w = f2bf(f.w);
      ((ushort4*)out)[i] = o;
    } else {
      int i = (bx - 2328) * 256 + threadIdx.x;
      if (i < 768) ((float4*)nrm)[i] = make_float4(0.f, 0.f, 0.f, 0.f);
    }
    return;
  }
  int idx = bx - 2331;
  int z = idx / 576, r2 = idx % 576;
  int tby = r2 / 24, tbx = r2 % 24;
  const float* W = (z == 0) ? W0 : (z == 1) ? W1 : (z == 2) ? W2 : W3;
  unsigned short* O = (z == 0) ? T0 : (z == 1) ? T1 : (z == 2) ? T2 : T3;
  const int gx = tbx * 32, gy = tby * 32;
  const int tx = threadIdx.x & 31, ty = threadIdx.x >> 5;
#pragma unroll
  for (int u = 0; u < 4; ++u) {
    int row = ty + u * 8;
    t[row][tx] = W[(size_t)(gy + row) * 768 + gx + tx];
  }
  __syncthreads();
#pragma unroll
  for (int u = 0; u < 4; ++u) {
    int row = ty + u * 8;
    O[(size_t)(gx + row) * 768 + gy + tx] = f2bf(t[tx][row]);
  }
}

// ---------------- projections, 8 waves: z=0:q->qb+qT(+iq_sq), 1:k->kb(+ik_sq), 2:v->vT, 3:ecls
__global__ __launch_bounds__(512, 2) void proj_gemm_kernel(
    const unsigned short* __restrict__ Ae, const unsigned short* __restrict__ Am,
    const unsigned short* __restrict__ Acls,
    const unsigned short* __restrict__ WqT, const unsigned short* __restrict__ WkT,
    const unsigned short* __restrict__ WvT, const unsigned short* __restrict__ WclsT,
    const float* __restrict__ bq, const float* __restrict__ bk,
    const float* __restrict__ bv, const float* __restrict__ bcls,
    unsigned short* __restrict__ qb, unsigned short* __restrict__ qT,
    unsigned short* __restrict__ kb, unsigned short* __restrict__ vT,
    float* __restrict__ ecls, float* __restrict__ iq_sq, float* __restrict__ ik_sq) {
  const int z = blockIdx.z;
  const int M = (z == 0) ? 1024 : (z == 3) ? 32 : 2048;
  const int bm = blockIdx.y * 128;
  if (bm >= M) return;
  const unsigned short* A = (z == 3) ? Acls : (z == 0) ? Ae : Am;
  const unsigned short* B = (z == 0) ? WqT : (z == 1) ? WkT : (z == 2) ? WvT : WclsT;
  const float* bias = (z == 0) ? bq : (z == 1) ? bk : (z == 2) ? bv : bcls;

  __shared__ unsigned short As[128 * 64];
  __shared__ unsigned short Bs[128 * 64];
  const int t = threadIdx.x;
  const int bn = blockIdx.x * 128;
  const int l = t & 63, w = t >> 6;        // 8 waves
  const int wm = w & 3, wn = w >> 2;       // 4 row strips (32) x 2 col strips (64)
  const int cg = l & 15, rq = l >> 4;

  f32x4 acc[2][4];
#pragma unroll
  for (int mi = 0; mi < 2; ++mi)
#pragma unroll
    for (int nj = 0; nj < 4; ++nj) { f32x4 zz = {0.f, 0.f, 0.f, 0.f}; acc[mi][nj] = zz; }

  for (int k0 = 0; k0 < 768; k0 += 64) {
    __syncthreads();
#pragma unroll
    for (int u = 0; u < 2; ++u) {
      int c = t + u * 512;
      int row = c >> 3, kc = c & 7;
      int gm = bm + row; gm = gm < M ? gm : M - 1;
      int4 av = *(const int4*)(A + (size_t)gm * 768 + k0 + kc * 8);
      *(int4*)(As + row * 64 + ((kc ^ (row & 7)) * 8)) = av;
      int4 bv4 = *(const int4*)(B + (size_t)(bn + row) * 768 + k0 + kc * 8);
      *(int4*)(Bs + row * 64 + ((kc ^ (row & 7)) * 8)) = bv4;
    }
    __syncthreads();
#pragma unroll
    for (int kk = 0; kk < 2; ++kk) {
      bfrag8 af[2], bf[4];
      const int kc = kk * 4 + rq;
#pragma unroll
      for (int mi = 0; mi < 2; ++mi) {
        int arow = wm * 32 + mi * 16 + cg;
        af[mi] = *(const bfrag8*)(As + arow * 64 + ((kc ^ (arow & 7)) * 8));
      }
#pragma unroll
      for (int nj = 0; nj < 4; ++nj) {
        int brow = wn * 64 + nj * 16 + cg;
        bf[nj] = *(const bfrag8*)(Bs + brow * 64 + ((kc ^ (brow & 7)) * 8));
      }
#pragma unroll
      for (int mi = 0; mi < 2; ++mi)
#pragma unroll
        for (int nj = 0; nj < 4; ++nj)
          acc[mi][nj] = __builtin_amdgcn_mfma_f32_16x16x32_bf16(af[mi], bf[nj], acc[mi][nj], 0, 0, 0);
    }
  }

  float p[2][4] = {};
#pragma unroll
  for (int mi = 0; mi < 2; ++mi) {
#pragma unroll
    for (int nj = 0; nj < 4; ++nj) {
      int gn = bn + wn * 64 + nj * 16 + cg;
      float bs = bias[gn];
#pragma unroll
      for (int r = 0; r < 4; ++r) {
        int gm = bm + wm * 32 + mi * 16 + rq * 4 + r;
        if (gm >= M) continue;
        float val = acc[mi][nj][r] + bs;
        if (z < 2) p[mi][r] += val * val;
        unsigned short bfv = f2bf(val);
        if (z == 0) {
          qb[(size_t)gm * 768 + gn] = bfv;
          int at = gm >> 5, j = gm & 31;
          qT[((size_t)at * 768 + gn) * 32 + j] = bfv;
        } else if (z == 1) kb[(size_t)gm * 768 + gn] = bfv;
        else if (z == 2) {
          int bb = gm >> 5, j = gm & 31;
          vT[((size_t)bb * 768 + gn) * 32 + j] = bfv;
        } else ecls[(size_t)gm * 768 + gn] = val;
      }
    }
  }
  if (z < 2) {
    float* nrm = (z == 0) ? iq_sq : ik_sq;
#pragma unroll
    for (int mi = 0; mi < 2; ++mi)
#pragma unroll
      for (int r = 0; r < 4; ++r) {
        float s = sum16(p[mi][r]);
        if (cg == 0) {
          int gm = bm + wm * 32 + mi * 16 + rq * 4 + r;
          atomicAdd(&nrm[gm], s);
        }
      }
  }
}

// ---------------- fused cos_sink + attn, 16 waves: 2 waves per (a,b) pair -------------------
// grid (32, 8): x = b-pair (bn=x*64), y = a-group (bm=y*128). 256 blocks = 1/CU, 4 waves/SIMD.
// wave w: pair p = w>>1 (a=p&3, b=p>>2), half q = w&1.
// launch_bounds(1024, 1): second arg follows CUDA minBlocks semantics -> VGPR cap 128 (not 64).
__global__ __launch_bounds__(1024, 1) void cos_attn_kernel(
    const unsigned short* __restrict__ qb, const unsigned short* __restrict__ kb,
    const float* __restrict__ iq_sq, const float* __restrict__ ik_sq,
    const unsigned short* __restrict__ qT,  // [32][768][32]
    const unsigned short* __restrict__ vT,  // [64][768][32]
    const float* __restrict__ ln1_g, const float* __restrict__ ln1_b,
    const float* __restrict__ Wsp, const float* __restrict__ bsp,
    const float* __restrict__ ln2_g, const float* __restrict__ ln2_b,
    const float* __restrict__ ecls,
    const float* __restrict__ entity_cls, const float* __restrict__ mention_cls,
    float* __restrict__ out) {
  __shared__ unsigned short vLds[2 * 768 * 32];            // 96 KB  [b_local][h][lb]
  __shared__ __align__(16) unsigned short scratch[12288];  // 24 KB: As(16K)+Bs(8K), reused as Tlds(16K)
  __shared__ float gabLds[4 * 768];                        // 12 KB  ln2_g*ecls[a_local]
  __shared__ float gwLds[768];                             // 3 KB   ln1_g*Wsp
  __shared__ float ldsIq[128], ldsIk[64];
  __shared__ float red[160];                               // 16 waves x 10 coefficient partials
  __shared__ float xch[1584];                              // 6.2 KB cross-wave exchange

  unsigned short* As = scratch;              // [128*64]
  unsigned short* Bs = scratch + 8192;       // [64*64]
  unsigned short* Tlds = scratch;            // [8 pairs][32][32], alive after GEMM only

  const int t = threadIdx.x;
  const int l = t & 63, w = t >> 6;          // w in 0..15
  const int p = w >> 1, q = w & 1;           // pair, half
  const int bm = blockIdx.y * 128, bn = blockIdx.x * 64;
  const int wm = p & 3, wn = p >> 2;         // a strip (32 rows), b strip (32 cols)
  const int cg = l & 15, rq = l >> 4;

  // ---- phase 0: per-block coefficient partials (visibility via first k-loop barrier) ----
  {
    float sgw = 0.f, sbw = 0.f, sga[4] = {}, sba[4] = {};
    for (int h = t; h < 768; h += 1024) {
      float g1 = ln1_g[h], b1 = ln1_b[h], wsp = Wsp[h];
      float g2 = ln2_g[h], b2 = ln2_b[h];
      float gw = g1 * wsp;
      gwLds[h] = gw;
      sgw += gw; sbw += b1 * wsp;
#pragma unroll
      for (int aa = 0; aa < 4; ++aa) {
        float ec = ecls[(size_t)((blockIdx.y << 2) + aa) * 768 + h];
        float gab = g2 * ec;
        gabLds[aa * 768 + h] = gab;
        sga[aa] += gab; sba[aa] += b2 * ec;
      }
    }
    sgw = sum16(sgw); sbw = sum16(sbw);
#pragma unroll
    for (int aa = 0; aa < 4; ++aa) { sga[aa] = sum16(sga[aa]); sba[aa] = sum16(sba[aa]); }
#pragma unroll
    for (int m = 16; m < 64; m <<= 1) {
      sgw += __shfl_xor(sgw, m); sbw += __shfl_xor(sbw, m);
#pragma unroll
      for (int aa = 0; aa < 4; ++aa) { sga[aa] += __shfl_xor(sga[aa], m); sba[aa] += __shfl_xor(sba[aa], m); }
    }
    if (l == 0) {
      red[w * 10 + 0] = sgw; red[w * 10 + 1] = sbw;
#pragma unroll
      for (int aa = 0; aa < 4; ++aa) { red[w * 10 + 2 + aa] = sga[aa]; red[w * 10 + 6 + aa] = sba[aa]; }
    }
  }
  if (t < 128) ldsIq[t] = iq_sq[bm + t];
  else if (t < 192) ldsIk[t - 128] = ik_sq[bn + t - 128];

  // ---- phase 1: cos GEMM (16x32 half-tile per wave) + vT->LDS copy interleaved ----
  // staging split: t<512 stage Bs, t>=512 stage vLds (512 int4/step x 12 steps = 96 KB exact)
  const int4* vsrc = (const int4*)(vT + (size_t)(blockIdx.x * 2) * 768 * 32);
  int4* vdst = (int4*)vLds;

  f32x4 acc[2];
#pragma unroll
  for (int nj = 0; nj < 2; ++nj) { f32x4 zz = {0.f, 0.f, 0.f, 0.f}; acc[nj] = zz; }

  for (int k0 = 0, s = 0; k0 < 768; k0 += 64, ++s) {
    __syncthreads();
    {
      int row = t >> 3, kc = t & 7;
      int4 av = *(const int4*)(qb + (size_t)(bm + row) * 768 + k0 + kc * 8);
      *(int4*)(As + row * 64 + ((kc ^ (row & 7)) * 8)) = av;
    }
    if (t < 512) {
      int row = t >> 3, kc = t & 7;
      int4 bv4 = *(const int4*)(kb + (size_t)(bn + row) * 768 + k0 + kc * 8);
      *(int4*)(Bs + row * 64 + ((kc ^ (row & 7)) * 8)) = bv4;
    } else {
      int tt = t - 512;
      vdst[tt + s * 512] = vsrc[tt + s * 512];
    }
    __syncthreads();
#pragma unroll
    for (int kk = 0; kk < 2; ++kk) {
      const int kc = kk * 4 + rq;
      const int arow = wm * 32 + q * 16 + cg;
      bfrag8 af = *(const bfrag8*)(As + arow * 64 + ((kc ^ (arow & 7)) * 8));
      bfrag8 bf[2];
#pragma unroll
      for (int nj = 0; nj < 2; ++nj) {
        int brow = wn * 32 + nj * 16 + cg;
        bf[nj] = *(const bfrag8*)(Bs + brow * 64 + ((kc ^ (brow & 7)) * 8));
      }
#pragma unroll
      for (int nj = 0; nj < 2; ++nj)
        acc[nj] = __builtin_amdgcn_mfma_f32_16x16x32_bf16(af, bf[nj], acc[nj], 0, 0, 0);
    }
  }

  // ---- phase 2: cosine normalize, exp, Sinkhorn (rows local; cols via partner exchange) ----
  float irow[4], icol[2];
#pragma unroll
  for (int r = 0; r < 4; ++r) {
    float sv = ldsIq[wm * 32 + q * 16 + rq * 4 + r];
    irow[r] = 1.0f / fmaxf(sqrtf(sv), 1e-8f);
  }
#pragma unroll
  for (int nj = 0; nj < 2; ++nj) {
    float sv = ldsIk[wn * 32 + nj * 16 + cg];
    icol[nj] = 1.0f / fmaxf(sqrtf(sv), 1e-8f);
  }
#pragma unroll
  for (int nj = 0; nj < 2; ++nj)
#pragma unroll
    for (int r = 0; r < 4; ++r)
      acc[nj][r] = __expf(acc[nj][r] * irow[r] * icol[nj] * 10.0f);

  for (int it = 0; it < 10; ++it) {
    // row normalize: rows are wave-local (16 rows), cols span both nj + cg -> sum16
#pragma unroll
    for (int r = 0; r < 4; ++r) {
      float rs = sum16(acc[0][r] + acc[1][r]);
      float rinv = __builtin_amdgcn_rcpf(rs);
      acc[0][r] *= rinv; acc[1][r] *= rinv;
    }
    // col normalize: local 16-row partial, exchange with partner wave
    float colp[2];
#pragma unroll
    for (int nj = 0; nj < 2; ++nj) {
      float cl = acc[nj][0] + acc[nj][1] + acc[nj][2] + acc[nj][3];
      cl += __shfl_xor(cl, 16); cl += __shfl_xor(cl, 32);
      colp[nj] = cl;
      if (rq == 0) xch[(it & 1) * 512 + w * 32 + nj * 16 + cg] = cl;
    }
    __syncthreads();
#pragma unroll
    for (int nj = 0; nj < 2; ++nj) {
      float cs = colp[nj] + xch[(it & 1) * 512 + (w ^ 1) * 32 + nj * 16 + cg];
      float cinv = __builtin_amdgcn_rcpf(cs);
#pragma unroll
      for (int r = 0; r < 4; ++r) acc[nj][r] *= cinv;
    }
  }

  // final L2 row-normalize (rows local)
#pragma unroll
  for (int r = 0; r < 4; ++r) {
    float ss = sum16(acc[0][r] * acc[0][r] + acc[1][r] * acc[1][r]);
    float tinv = 1.0f / fmaxf(sqrtf(ss), 1e-12f);
    acc[0][r] *= tinv; acc[1][r] *= tinv;
  }

  // ---- phase 3: T -> LDS (aliases dead As/Bs; barrier on both sides) ----
  __syncthreads();   // all waves past their last As/Bs fragment read
  {
    unsigned short* base = Tlds + (p << 10);
#pragma unroll
    for (int nj = 0; nj < 2; ++nj)
#pragma unroll
      for (int r = 0; r < 4; ++r)
        base[(q * 16 + rq * 4 + r) * 32 + nj * 16 + cg] = f2bf(acc[nj][r]);
  }
  __syncthreads();   // Tlds + vLds ready for everyone

  // ---- phase 4: attention. pair p: b_local = p>>2, a_local = p&3; half q splits h-tiles ----
  const int bl = p >> 2, ah = p & 3;
  const int b_g = (blockIdx.x << 1) + bl;
  const int a_g = (blockIdx.y << 2) + ah;
  const unsigned short* vbase = vLds + bl * 24576;

  float sgw_f = 0.f, sbw_f = 0.f, sga_f = 0.f, sba_f = 0.f;
#pragma unroll
  for (int wv = 0; wv < 16; ++wv) {
    sgw_f += red[wv * 10 + 0]; sbw_f += red[wv * 10 + 1];
    sga_f += red[wv * 10 + 2 + ah]; sba_f += red[wv * 10 + 6 + ah];
  }
  sbw_f += bsp[0];

  const unsigned short* qTa = qT + (size_t)a_g * 24576;
  const unsigned short* Tp = Tlds + (p << 10);
  bfrag8 af[2], afI[2];
#pragma unroll
  for (int mi = 0; mi < 2; ++mi) {
    af[mi] = *(const bfrag8*)(Tp + (mi * 16 + cg) * 32 + rq * 8);
    int row = mi * 16 + cg;
    bfrag8 fI;
#pragma unroll
    for (int u = 0; u < 8; ++u) fI[u] = (row == rq * 8 + u) ? (short)0x3F80 : (short)0;
    afI[mi] = fI;
  }

  // ---- pass 1: row stats over this wave's 24 h-tiles ----
  float s1[2][4] = {}, s2[2][4] = {}, a1[2][4] = {};
#pragma unroll 4
  for (int j = 0; j < 24; ++j) {
    int nj = q * 24 + j;
    int h = nj * 16 + cg;
    bfrag8 vf = *(const bfrag8*)(vbase + h * 32 + rq * 8);
    bfrag8 qf = *(const bfrag8*)(qTa + (size_t)h * 32 + rq * 8);
    float gw = gwLds[h];
#pragma unroll
    for (int mi = 0; mi < 2; ++mi) {
      f32x4 zz = {0.f, 0.f, 0.f, 0.f};
      f32x4 pr = __builtin_amdgcn_mfma_f32_16x16x32_bf16(af[mi], vf, zz, 0, 0, 0);
      f32x4 x4 = __builtin_amdgcn_mfma_f32_16x16x32_bf16(afI[mi], qf, pr, 0, 0, 0);
#pragma unroll
      for (int r = 0; r < 4; ++r) {
        float x = x4[r];
        s1[mi][r] += x; s2[mi][r] += x * x; a1[mi][r] += x * gw;
      }
    }
  }
#pragma unroll
  for (int mi = 0; mi < 2; ++mi)
#pragma unroll
    for (int r = 0; r < 4; ++r) {
      s1[mi][r] = sum16(s1[mi][r]);
      s2[mi][r] = sum16(s2[mi][r]);
      a1[mi][r] = sum16(a1[mi][r]);
    }
  // combine with partner wave
  if (cg == 0) {
#pragma unroll
    for (int mi = 0; mi < 2; ++mi)
#pragma unroll
      for (int r = 0; r < 4; ++r) {
        int row = mi * 16 + rq * 4 + r;
        xch[(w * 3 + 0) * 32 + row] = s1[mi][r];
        xch[(w * 3 + 1) * 32 + row] = s2[mi][r];
        xch[(w * 3 + 2) * 32 + row] = a1[mi][r];
      }
  }
  __syncthreads();
  {
    const int pw = w ^ 1;
#pragma unroll
    for (int mi = 0; mi < 2; ++mi)
#pragma unroll
      for (int r = 0; r < 4; ++r) {
        int row = mi * 16 + rq * 4 + r;
        s1[mi][r] += xch[(pw * 3 + 0) * 32 + row];
        s2[mi][r] += xch[(pw * 3 + 1) * 32 + row];
        a1[mi][r] += xch[(pw * 3 + 2) * 32 + row];
      }
  }

  // ---- logits, softmax, u, c0 (computed redundantly in both halves) ----
  float uu[2][4], c0;
  {
    float mean[2][4], rstd[2][4], logit[2][4];
#pragma unroll
    for (int mi = 0; mi < 2; ++mi)
#pragma unroll
      for (int r = 0; r < 4; ++r) {
        float m1 = s1[mi][r] * (1.0f / 768.0f);
        float var = s2[mi][r] * (1.0f / 768.0f) - m1 * m1;
        float rs = rsqrtf(var + 1e-5f);
        mean[mi][r] = m1; rstd[mi][r] = rs;
        logit[mi][r] = rs * (a1[mi][r] - m1 * sgw_f) + sbw_f;
      }
    float mx = logit[0][0];
#pragma unroll
    for (int mi = 0; mi < 2; ++mi)
#pragma unroll
      for (int r = 0; r < 4; ++r) mx = fmaxf(mx, logit[mi][r]);
    mx = fmaxf(mx, __shfl_xor(mx, 16)); mx = fmaxf(mx, __shfl_xor(mx, 32));
    float se = 0.f, ee[2][4];
#pragma unroll
    for (int mi = 0; mi < 2; ++mi)
#pragma unroll
      for (int r = 0; r < 4; ++r) { ee[mi][r] = __expf(logit[mi][r] - mx); se += ee[mi][r]; }
    se += __shfl_xor(se, 16); se += __shfl_xor(se, 32);
    const float sinv = __builtin_amdgcn_rcpf(se);
    float c0a = 0.f;
#pragma unroll
    for (int mi = 0; mi < 2; ++mi)
#pragma unroll
      for (int r = 0; r < 4; ++r) {
        uu[mi][r] = ee[mi][r] * sinv * rstd[mi][r];
        c0a += uu[mi][r] * mean[mi][r];
      }
    c0a += __shfl_xor(c0a, 16); c0a += __shfl_xor(c0a, 32);
    c0 = c0a;
  }

  // ---- pass 2: streaming pooled -> LN2 stats over this wave's 24 h-tiles ----
  float ps = 0.f, pq = 0.f, spc = 0.f;
#pragma unroll 4
  for (int j = 0; j < 24; ++j) {
    int nj = q * 24 + j;
    int h = nj * 16 + cg;
    bfrag8 vf = *(const bfrag8*)(vbase + h * 32 + rq * 8);
    bfrag8 qf = *(const bfrag8*)(qTa + (size_t)h * 32 + rq * 8);
    float pp = 0.f;
#pragma unroll
    for (int mi = 0; mi < 2; ++mi) {
      f32x4 zz = {0.f, 0.f, 0.f, 0.f};
      f32x4 pr = __builtin_amdgcn_mfma_f32_16x16x32_bf16(af[mi], vf, zz, 0, 0, 0);
      f32x4 x4 = __builtin_amdgcn_mfma_f32_16x16x32_bf16(afI[mi], qf, pr, 0, 0, 0);
#pragma unroll
      for (int r = 0; r < 4; ++r) pp += uu[mi][r] * x4[r];
    }
    pp += __shfl_xor(pp, 16); pp += __shfl_xor(pp, 32);
    float pooled = ln1_g[h] * (pp - c0) + ln1_b[h];
    ps += pooled; pq += pooled * pooled;
    spc += pooled * gabLds[ah * 768 + h];
  }
  ps = sum16(ps); pq = sum16(pq); spc = sum16(spc);
  // combine with partner
  if (l == 0) {
    xch[1536 + w * 3 + 0] = ps;
    xch[1536 + w * 3 + 1] = pq;
    xch[1536 + w * 3 + 2] = spc;
  }
  __syncthreads();
  {
    const int pw = w ^ 1;
    ps += xch[1536 + pw * 3 + 0];
    pq += xch[1536 + pw * 3 + 1];
    spc += xch[1536 + pw * 3 + 2];
  }
  const float m2 = ps * (1.0f / 768.0f);
  const float var2 = pq * (1.0f / 768.0f) - m2 * m2;
  const float rs2 = rsqrtf(var2 + 1e-5f);
  const float* ea = entity_cls + (size_t)a_g * 768;
  const float* mb = mention_cls + (size_t)b_g * 768;
  float sg = 0.f;
#pragma unroll
  for (int u = 0; u < 12; ++u) sg += mb[l * 12 + u] * ea[l * 12 + u];
  sg = sum16(sg);
  sg += __shfl_xor(sg, 16); sg += __shfl_xor(sg, 32);
  float tot = rs2 * (spc - m2 * sga_f) + sba_f + sg;
  if (l == 0 && q == 0) out[b_g * 32 + a_g] = 0.5f * tot;
}

extern "C" void kernel_launch(void* const* d_in, const int* in_sizes, int n_in,
                              void* d_out, int out_size, void* d_ws, size_t ws_size,
                              hipStream_t stream) {
  const float* entity_cls     = (const float*)d_in[0];
  const float* entity_tokens  = (const float*)d_in[1];
  const float* mention_cls    = (const float*)d_in[2];
  const float* mention_tokens = (const float*)d_in[3];
  const float* Wq = (const float*)d_in[4];   const float* bq = (const float*)d_in[5];
  const float* Wk = (const float*)d_in[6];   const float* bk = (const float*)d_in[7];
  const float* Wv = (const float*)d_in[8];   const float* bv = (const float*)d_in[9];
  const float* ln1_g = (const float*)d_in[10]; const float* ln1_b = (const float*)d_in[11];
  const float* Wcls = (const float*)d_in[12];  const float* bcls = (const float*)d_in[13];
  const float* Wsp = (const float*)d_in[14];   const float* bsp = (const float*)d_in[15];
  const float* ln2_g = (const float*)d_in[16]; const float* ln2_b = (const float*)d_in[17];
  float* out = (float*)d_out;

  float* ws     = (float*)d_ws;
  float* ecls   = ws;                          // 32*768
  float* iq_sq  = ecls + 24576;                // 1024
  float* ik_sq  = iq_sq + 1024;                // 2048
  // (aux region retained for layout compatibility; unused now)
  unsigned short* qb = (unsigned short*)(ws + 55168);     // 1024*768
  unsigned short* qT = qb + 786432;                       // 32*768*32
  unsigned short* kb = qT + 786432;                       // 2048*768
  unsigned short* vT = kb + 1572864;                      // 64*768*32
  char* R = (char*)(vT + 1572864);
  unsigned short* Ae    = (unsigned short*)R;
  unsigned short* Am    = Ae + 786432;
  unsigned short* Acls  = Am + 1572864;
  unsigned short* WqT   = Acls + 24576;
  unsigned short* WkT   = WqT + 589824;
  unsigned short* WvT   = WkT + 589824;
  unsigned short* WclsT = WvT + 589824;

  prep_kernel<<<dim3(4635), dim3(256), 0, stream>>>(
      entity_tokens, mention_tokens, entity_cls, Ae, Am, Acls, iq_sq,
      Wq, Wk, Wv, Wcls, WqT, WkT, WvT, WclsT);
  proj_gemm_kernel<<<dim3(6, 16, 4), dim3(512), 0, stream>>>(
      Ae, Am, Acls, WqT, WkT, WvT, WclsT, bq, bk, bv, bcls,
      qb, qT, kb, vT, ecls, iq_sq, ik_sq);
  cos_attn_kernel<<<dim3(32, 8), dim3(1024), 0, stream>>>(
      qb, kb, iq_sq, ik_sq, qT, vT,
      ln1_g, ln1_b, Wsp, bsp, ln2_g, ln2_b,
      ecls, entity_cls, mention_cls, out);
}

// Round 7
// 174.250 us; speedup vs baseline: 1.0843x; 1.0843x over previous
//
#include <hip/hip_runtime.h>
#include <math.h>

// Shapes (fixed): Na=32, La=32, B=64, Lb=32, Din=H=768.

typedef __attribute__((ext_vector_type(8))) short bfrag8;   // 8 bf16 in 4 VGPRs
typedef __attribute__((ext_vector_type(4))) float f32x4;

__device__ __forceinline__ unsigned short f2bf(float x) {
  union { float f; unsigned u; } v; v.f = x;
  unsigned r = v.u + 0x7fffu + ((v.u >> 16) & 1u);
  return (unsigned short)(r >> 16);
}

// DPP-based add-reduction over 16-lane rows (VALU pipe; avoids ds_swizzle latency).
template <int CTRL>
__device__ __forceinline__ float dpp_add(float x) {
  union { float f; int i; } a, b;
  a.f = x;
  b.i = __builtin_amdgcn_update_dpp(0, a.i, CTRL, 0xf, 0xf, true);
  return x + b.f;
}
// full sum over the 16 lanes of a DPP row (cg dimension), result in all 16 lanes
__device__ __forceinline__ float sum16(float x) {
  x = dpp_add<0xB1>(x);    // quad_perm [1,0,3,2]  : xor 1
  x = dpp_add<0x4E>(x);    // quad_perm [2,3,0,1]  : xor 2
  x = dpp_add<0x124>(x);   // row_ror:4
  x = dpp_add<0x128>(x);   // row_ror:8
  return x;
}

// ---------------- prep: casts (3 tensors) + zero norm buffer + 4 weight transposes -------------
__global__ __launch_bounds__(256) void prep_kernel(
    const float* __restrict__ a0, const float* __restrict__ a1, const float* __restrict__ a2,
    unsigned short* __restrict__ o0, unsigned short* __restrict__ o1, unsigned short* __restrict__ o2,
    float* __restrict__ nrm,
    const float* __restrict__ W0, const float* __restrict__ W1,
    const float* __restrict__ W2, const float* __restrict__ W3,
    unsigned short* __restrict__ T0, unsigned short* __restrict__ T1,
    unsigned short* __restrict__ T2, unsigned short* __restrict__ T3) {
  __shared__ float t[32][33];
  int bx = blockIdx.x;
  if (bx < 2331) {
    if (bx < 2328) {
      const float* in; unsigned short* out; int i, n4;
      if (bx < 768)       { in = a0; out = o0; i = bx * 256 + threadIdx.x;          n4 = 196608; }
      else if (bx < 2304) { in = a1; out = o1; i = (bx - 768) * 256 + threadIdx.x;  n4 = 393216; }
      else                { in = a2; out = o2; i = (bx - 2304) * 256 + threadIdx.x; n4 = 6144; }
      if (i >= n4) return;
      float4 f = ((const float4*)in)[i];
      ushort4 o;
      o.x = f2bf(f.x); o.y = f2bf(f.y); o.z = f2bf(f.z); o.w = f2bf(f.w);
      ((ushort4*)out)[i] = o;
    } else {
      int i = (bx - 2328) * 256 + threadIdx.x;
      if (i < 768) ((float4*)nrm)[i] = make_float4(0.f, 0.f, 0.f, 0.f);
    }
    return;
  }
  int idx = bx - 2331;
  int z = idx / 576, r2 = idx % 576;
  int tby = r2 / 24, tbx = r2 % 24;
  const float* W = (z == 0) ? W0 : (z == 1) ? W1 : (z == 2) ? W2 : W3;
  unsigned short* O = (z == 0) ? T0 : (z == 1) ? T1 : (z == 2) ? T2 : T3;
  const int gx = tbx * 32, gy = tby * 32;
  const int tx = threadIdx.x & 31, ty = threadIdx.x >> 5;
#pragma unroll
  for (int u = 0; u < 4; ++u) {
    int row = ty + u * 8;
    t[row][tx] = W[(size_t)(gy + row) * 768 + gx + tx];
  }
  __syncthreads();
#pragma unroll
  for (int u = 0; u < 4; ++u) {
    int row = ty + u * 8;
    O[(size_t)(gx + row) * 768 + gy + tx] = f2bf(t[tx][row]);
  }
}

// ---------------- projections, 8 waves: z=0:q->qb+qT(+iq_sq), 1:k->kb(+ik_sq), 2:v->vT, 3:ecls
__global__ __launch_bounds__(512, 2) void proj_gemm_kernel(
    const unsigned short* __restrict__ Ae, const unsigned short* __restrict__ Am,
    const unsigned short* __restrict__ Acls,
    const unsigned short* __restrict__ WqT, const unsigned short* __restrict__ WkT,
    const unsigned short* __restrict__ WvT, const unsigned short* __restrict__ WclsT,
    const float* __restrict__ bq, const float* __restrict__ bk,
    const float* __restrict__ bv, const float* __restrict__ bcls,
    unsigned short* __restrict__ qb, unsigned short* __restrict__ qT,
    unsigned short* __restrict__ kb, unsigned short* __restrict__ vT,
    float* __restrict__ ecls, float* __restrict__ iq_sq, float* __restrict__ ik_sq) {
  const int z = blockIdx.z;
  const int M = (z == 0) ? 1024 : (z == 3) ? 32 : 2048;
  const int bm = blockIdx.y * 128;
  if (bm >= M) return;
  const unsigned short* A = (z == 3) ? Acls : (z == 0) ? Ae : Am;
  const unsigned short* B = (z == 0) ? WqT : (z == 1) ? WkT : (z == 2) ? WvT : WclsT;
  const float* bias = (z == 0) ? bq : (z == 1) ? bk : (z == 2) ? bv : bcls;

  __shared__ unsigned short As[128 * 64];
  __shared__ unsigned short Bs[128 * 64];
  const int t = threadIdx.x;
  const int bn = blockIdx.x * 128;
  const int l = t & 63, w = t >> 6;        // 8 waves
  const int wm = w & 3, wn = w >> 2;       // 4 row strips (32) x 2 col strips (64)
  const int cg = l & 15, rq = l >> 4;

  f32x4 acc[2][4];
#pragma unroll
  for (int mi = 0; mi < 2; ++mi)
#pragma unroll
    for (int nj = 0; nj < 4; ++nj) { f32x4 zz = {0.f, 0.f, 0.f, 0.f}; acc[mi][nj] = zz; }

  for (int k0 = 0; k0 < 768; k0 += 64) {
    __syncthreads();
#pragma unroll
    for (int u = 0; u < 2; ++u) {
      int c = t + u * 512;
      int row = c >> 3, kc = c & 7;
      int gm = bm + row; gm = gm < M ? gm : M - 1;
      int4 av = *(const int4*)(A + (size_t)gm * 768 + k0 + kc * 8);
      *(int4*)(As + row * 64 + ((kc ^ (row & 7)) * 8)) = av;
      int4 bv4 = *(const int4*)(B + (size_t)(bn + row) * 768 + k0 + kc * 8);
      *(int4*)(Bs + row * 64 + ((kc ^ (row & 7)) * 8)) = bv4;
    }
    __syncthreads();
#pragma unroll
    for (int kk = 0; kk < 2; ++kk) {
      bfrag8 af[2], bf[4];
      const int kc = kk * 4 + rq;
#pragma unroll
      for (int mi = 0; mi < 2; ++mi) {
        int arow = wm * 32 + mi * 16 + cg;
        af[mi] = *(const bfrag8*)(As + arow * 64 + ((kc ^ (arow & 7)) * 8));
      }
#pragma unroll
      for (int nj = 0; nj < 4; ++nj) {
        int brow = wn * 64 + nj * 16 + cg;
        bf[nj] = *(const bfrag8*)(Bs + brow * 64 + ((kc ^ (brow & 7)) * 8));
      }
#pragma unroll
      for (int mi = 0; mi < 2; ++mi)
#pragma unroll
        for (int nj = 0; nj < 4; ++nj)
          acc[mi][nj] = __builtin_amdgcn_mfma_f32_16x16x32_bf16(af[mi], bf[nj], acc[mi][nj], 0, 0, 0);
    }
  }

  float p[2][4] = {};
#pragma unroll
  for (int mi = 0; mi < 2; ++mi) {
#pragma unroll
    for (int nj = 0; nj < 4; ++nj) {
      int gn = bn + wn * 64 + nj * 16 + cg;
      float bs = bias[gn];
#pragma unroll
      for (int r = 0; r < 4; ++r) {
        int gm = bm + wm * 32 + mi * 16 + rq * 4 + r;
        if (gm >= M) continue;
        float val = acc[mi][nj][r] + bs;
        if (z < 2) p[mi][r] += val * val;
        unsigned short bfv = f2bf(val);
        if (z == 0) {
          qb[(size_t)gm * 768 + gn] = bfv;
          int at = gm >> 5, j = gm & 31;
          qT[((size_t)at * 768 + gn) * 32 + j] = bfv;
        } else if (z == 1) kb[(size_t)gm * 768 + gn] = bfv;
        else if (z == 2) {
          int bb = gm >> 5, j = gm & 31;
          vT[((size_t)bb * 768 + gn) * 32 + j] = bfv;
        } else ecls[(size_t)gm * 768 + gn] = val;
      }
    }
  }
  if (z < 2) {
    float* nrm = (z == 0) ? iq_sq : ik_sq;
#pragma unroll
    for (int mi = 0; mi < 2; ++mi)
#pragma unroll
      for (int r = 0; r < 4; ++r) {
        float s = sum16(p[mi][r]);
        if (cg == 0) {
          int gm = bm + wm * 32 + mi * 16 + rq * 4 + r;
          atomicAdd(&nrm[gm], s);
        }
      }
  }
}

// ---------------- fused cos_sink + attn: ONE b per block, 8 waves, 2 waves/pair --------------
// grid (64, 8): x = b (bn = x*32 k-rows), y = a-group (bm = y*128). 512 blocks = 2/CU,
// 16 waves/CU = 4 waves/SIMD. LDS ~75 KB so 2 blocks co-resident.
// wave w: pair p = w>>1 (a_local), half q = w&1.
__global__ __launch_bounds__(512, 2) void cos_attn_kernel(
    const unsigned short* __restrict__ qb, const unsigned short* __restrict__ kb,
    const float* __restrict__ iq_sq, const float* __restrict__ ik_sq,
    const unsigned short* __restrict__ qT,  // [32][768][32]
    const unsigned short* __restrict__ vT,  // [64][768][32]
    const float* __restrict__ ln1_g, const float* __restrict__ ln1_b,
    const float* __restrict__ Wsp, const float* __restrict__ bsp,
    const float* __restrict__ ln2_g, const float* __restrict__ ln2_b,
    const float* __restrict__ ecls,
    const float* __restrict__ entity_cls, const float* __restrict__ mention_cls,
    float* __restrict__ out) {
  __shared__ unsigned short vLds[768 * 32];                // 48 KB  [h][lb] for this block's b
  __shared__ __align__(16) unsigned short scratch[10240];  // 20 KB: As(16K)+Bs(4K); Tlds(8K) aliases
  __shared__ float gwLds[768];                             // 3 KB   ln1_g*Wsp
  __shared__ float ldsIq[128], ldsIk[32];
  __shared__ float red[80];                                // 8 waves x 10 coefficient partials
  __shared__ float xch[792];                               // sinkhorn [0,512) / pass1 [0,768) / pass2 [768,792)

  unsigned short* As = scratch;              // [128*64]
  unsigned short* Bs = scratch + 8192;       // [32*64]
  unsigned short* Tlds = scratch;            // [4 pairs][32][32], alive after GEMM only

  const int t = threadIdx.x;
  const int l = t & 63, w = t >> 6;          // w in 0..7
  const int p = w >> 1, q = w & 1;           // pair(= a_local), half
  const int bm = blockIdx.y * 128;
  const int b_g = blockIdx.x;
  const int cg = l & 15, rq = l >> 4;

  // ---- phase 0: per-block coefficient partials (visibility via first k-loop barrier) ----
  {
    float sgw = 0.f, sbw = 0.f, sga[4] = {}, sba[4] = {};
    for (int h = t; h < 768; h += 512) {
      float g1 = ln1_g[h], b1 = ln1_b[h], wsp = Wsp[h];
      float g2 = ln2_g[h], b2 = ln2_b[h];
      float gw = g1 * wsp;
      gwLds[h] = gw;
      sgw += gw; sbw += b1 * wsp;
#pragma unroll
      for (int aa = 0; aa < 4; ++aa) {
        float ec = ecls[(size_t)((blockIdx.y << 2) + aa) * 768 + h];
        sga[aa] += g2 * ec; sba[aa] += b2 * ec;
      }
    }
    sgw = sum16(sgw); sbw = sum16(sbw);
#pragma unroll
    for (int aa = 0; aa < 4; ++aa) { sga[aa] = sum16(sga[aa]); sba[aa] = sum16(sba[aa]); }
#pragma unroll
    for (int m = 16; m < 64; m <<= 1) {
      sgw += __shfl_xor(sgw, m); sbw += __shfl_xor(sbw, m);
#pragma unroll
      for (int aa = 0; aa < 4; ++aa) { sga[aa] += __shfl_xor(sga[aa], m); sba[aa] += __shfl_xor(sba[aa], m); }
    }
    if (l == 0) {
      red[w * 10 + 0] = sgw; red[w * 10 + 1] = sbw;
#pragma unroll
      for (int aa = 0; aa < 4; ++aa) { red[w * 10 + 2 + aa] = sga[aa]; red[w * 10 + 6 + aa] = sba[aa]; }
    }
  }
  if (t < 128) ldsIq[t] = iq_sq[bm + t];
  else if (t < 160) ldsIk[t - 128] = ik_sq[b_g * 32 + (t - 128)];

  // ---- phase 1: cos GEMM (16x32 half-tile per wave) + vT->LDS copy interleaved ----
  // staging: all threads 2x As; t<256 Bs; t in [256,512) vLds (256 int4/step x 12 = 48 KB exact)
  const int4* vsrc = (const int4*)(vT + (size_t)b_g * 768 * 32);
  int4* vdst = (int4*)vLds;

  f32x4 acc[2];
#pragma unroll
  for (int nj = 0; nj < 2; ++nj) { f32x4 zz = {0.f, 0.f, 0.f, 0.f}; acc[nj] = zz; }

  for (int k0 = 0, s = 0; k0 < 768; k0 += 64, ++s) {
    __syncthreads();
#pragma unroll
    for (int u = 0; u < 2; ++u) {
      int c = t + u * 512;
      int row = c >> 3, kc = c & 7;
      int4 av = *(const int4*)(qb + (size_t)(bm + row) * 768 + k0 + kc * 8);
      *(int4*)(As + row * 64 + ((kc ^ (row & 7)) * 8)) = av;
    }
    if (t < 256) {
      int row = t >> 3, kc = t & 7;
      int4 bv4 = *(const int4*)(kb + (size_t)(b_g * 32 + row) * 768 + k0 + kc * 8);
      *(int4*)(Bs + row * 64 + ((kc ^ (row & 7)) * 8)) = bv4;
    } else {
      int tt = t - 256;
      vdst[tt + s * 256] = vsrc[tt + s * 256];
    }
    __syncthreads();
#pragma unroll
    for (int kk = 0; kk < 2; ++kk) {
      const int kc = kk * 4 + rq;
      const int arow = p * 32 + q * 16 + cg;
      bfrag8 af = *(const bfrag8*)(As + arow * 64 + ((kc ^ (arow & 7)) * 8));
      bfrag8 bf[2];
#pragma unroll
      for (int nj = 0; nj < 2; ++nj) {
        int brow = nj * 16 + cg;
        bf[nj] = *(const bfrag8*)(Bs + brow * 64 + ((kc ^ (brow & 7)) * 8));
      }
#pragma unroll
      for (int nj = 0; nj < 2; ++nj)
        acc[nj] = __builtin_amdgcn_mfma_f32_16x16x32_bf16(af, bf[nj], acc[nj], 0, 0, 0);
    }
  }

  // ---- phase 2: cosine normalize, exp, Sinkhorn (rows local; cols via partner exchange) ----
  float irow[4], icol[2];
#pragma unroll
  for (int r = 0; r < 4; ++r) {
    float sv = ldsIq[p * 32 + q * 16 + rq * 4 + r];
    irow[r] = 1.0f / fmaxf(sqrtf(sv), 1e-8f);
  }
#pragma unroll
  for (int nj = 0; nj < 2; ++nj) {
    float sv = ldsIk[nj * 16 + cg];
    icol[nj] = 1.0f / fmaxf(sqrtf(sv), 1e-8f);
  }
#pragma unroll
  for (int nj = 0; nj < 2; ++nj)
#pragma unroll
    for (int r = 0; r < 4; ++r)
      acc[nj][r] = __expf(acc[nj][r] * irow[r] * icol[nj] * 10.0f);

  for (int it = 0; it < 10; ++it) {
    // row normalize: 16 rows wave-local; row spans both nj + cg -> sum16
#pragma unroll
    for (int r = 0; r < 4; ++r) {
      float rs = sum16(acc[0][r] + acc[1][r]);
      float rinv = __builtin_amdgcn_rcpf(rs);
      acc[0][r] *= rinv; acc[1][r] *= rinv;
    }
    // col normalize: local 16-row partial, exchange with partner wave
    float colp[2];
#pragma unroll
    for (int nj = 0; nj < 2; ++nj) {
      float cl = acc[nj][0] + acc[nj][1] + acc[nj][2] + acc[nj][3];
      cl += __shfl_xor(cl, 16); cl += __shfl_xor(cl, 32);
      colp[nj] = cl;
      if (rq == 0) xch[(it & 1) * 256 + w * 32 + nj * 16 + cg] = cl;
    }
    __syncthreads();
#pragma unroll
    for (int nj = 0; nj < 2; ++nj) {
      float cs = colp[nj] + xch[(it & 1) * 256 + (w ^ 1) * 32 + nj * 16 + cg];
      float cinv = __builtin_amdgcn_rcpf(cs);
#pragma unroll
      for (int r = 0; r < 4; ++r) acc[nj][r] *= cinv;
    }
  }

  // final L2 row-normalize (rows local)
#pragma unroll
  for (int r = 0; r < 4; ++r) {
    float ss = sum16(acc[0][r] * acc[0][r] + acc[1][r] * acc[1][r]);
    float tinv = 1.0f / fmaxf(sqrtf(ss), 1e-12f);
    acc[0][r] *= tinv; acc[1][r] *= tinv;
  }

  // ---- phase 3: T -> LDS (aliases dead As/Bs; barrier on both sides) ----
  __syncthreads();   // all waves past their last As/Bs fragment read
  {
    unsigned short* base = Tlds + (p << 10);
#pragma unroll
    for (int nj = 0; nj < 2; ++nj)
#pragma unroll
      for (int r = 0; r < 4; ++r)
        base[(q * 16 + rq * 4 + r) * 32 + nj * 16 + cg] = f2bf(acc[nj][r]);
  }
  __syncthreads();   // Tlds + vLds ready for everyone

  // ---- phase 4: attention. pair p = a_local (b shared by block); half q splits h-tiles ----
  const int a_g = (blockIdx.y << 2) + p;

  float sgw_f = 0.f, sbw_f = 0.f, sga_f = 0.f, sba_f = 0.f;
#pragma unroll
  for (int wv = 0; wv < 8; ++wv) {
    sgw_f += red[wv * 10 + 0]; sbw_f += red[wv * 10 + 1];
    sga_f += red[wv * 10 + 2 + p]; sba_f += red[wv * 10 + 6 + p];
  }
  sbw_f += bsp[0];

  const unsigned short* qTa = qT + (size_t)a_g * 24576;
  const float* gabg = ecls + (size_t)a_g * 768;
  const unsigned short* Tp = Tlds + (p << 10);
  bfrag8 af[2], afI[2];
#pragma unroll
  for (int mi = 0; mi < 2; ++mi) {
    af[mi] = *(const bfrag8*)(Tp + (mi * 16 + cg) * 32 + rq * 8);
    int row = mi * 16 + cg;
    bfrag8 fI;
#pragma unroll
    for (int u = 0; u < 8; ++u) fI[u] = (row == rq * 8 + u) ? (short)0x3F80 : (short)0;
    afI[mi] = fI;
  }

  // ---- pass 1: row stats over this wave's 24 h-tiles ----
  float s1[2][4] = {}, s2[2][4] = {}, a1[2][4] = {};
#pragma unroll 4
  for (int j = 0; j < 24; ++j) {
    int nj = q * 24 + j;
    int h = nj * 16 + cg;
    bfrag8 vf = *(const bfrag8*)(vLds + h * 32 + rq * 8);
    bfrag8 qf = *(const bfrag8*)(qTa + (size_t)h * 32 + rq * 8);
    float gw = gwLds[h];
#pragma unroll
    for (int mi = 0; mi < 2; ++mi) {
      f32x4 zz = {0.f, 0.f, 0.f, 0.f};
      f32x4 pr = __builtin_amdgcn_mfma_f32_16x16x32_bf16(af[mi], vf, zz, 0, 0, 0);
      f32x4 x4 = __builtin_amdgcn_mfma_f32_16x16x32_bf16(afI[mi], qf, pr, 0, 0, 0);
#pragma unroll
      for (int r = 0; r < 4; ++r) {
        float x = x4[r];
        s1[mi][r] += x; s2[mi][r] += x * x; a1[mi][r] += x * gw;
      }
    }
  }
#pragma unroll
  for (int mi = 0; mi < 2; ++mi)
#pragma unroll
    for (int r = 0; r < 4; ++r) {
      s1[mi][r] = sum16(s1[mi][r]);
      s2[mi][r] = sum16(s2[mi][r]);
      a1[mi][r] = sum16(a1[mi][r]);
    }
  // combine with partner wave
  if (cg == 0) {
#pragma unroll
    for (int mi = 0; mi < 2; ++mi)
#pragma unroll
      for (int r = 0; r < 4; ++r) {
        int row = mi * 16 + rq * 4 + r;
        xch[(w * 3 + 0) * 32 + row] = s1[mi][r];
        xch[(w * 3 + 1) * 32 + row] = s2[mi][r];
        xch[(w * 3 + 2) * 32 + row] = a1[mi][r];
      }
  }
  __syncthreads();
  {
    const int pw = w ^ 1;
#pragma unroll
    for (int mi = 0; mi < 2; ++mi)
#pragma unroll
      for (int r = 0; r < 4; ++r) {
        int row = mi * 16 + rq * 4 + r;
        s1[mi][r] += xch[(pw * 3 + 0) * 32 + row];
        s2[mi][r] += xch[(pw * 3 + 1) * 32 + row];
        a1[mi][r] += xch[(pw * 3 + 2) * 32 + row];
      }
  }

  // ---- logits, softmax, u, c0 (computed redundantly in both halves) ----
  float uu[2][4], c0;
  {
    float mean[2][4], rstd[2][4], logit[2][4];
#pragma unroll
    for (int mi = 0; mi < 2; ++mi)
#pragma unroll
      for (int r = 0; r < 4; ++r) {
        float m1 = s1[mi][r] * (1.0f / 768.0f);
        float var = s2[mi][r] * (1.0f / 768.0f) - m1 * m1;
        float rs = rsqrtf(var + 1e-5f);
        mean[mi][r] = m1; rstd[mi][r] = rs;
        logit[mi][r] = rs * (a1[mi][r] - m1 * sgw_f) + sbw_f;
      }
    float mx = logit[0][0];
#pragma unroll
    for (int mi = 0; mi < 2; ++mi)
#pragma unroll
      for (int r = 0; r < 4; ++r) mx = fmaxf(mx, logit[mi][r]);
    mx = fmaxf(mx, __shfl_xor(mx, 16)); mx = fmaxf(mx, __shfl_xor(mx, 32));
    float se = 0.f, ee[2][4];
#pragma unroll
    for (int mi = 0; mi < 2; ++mi)
#pragma unroll
      for (int r = 0; r < 4; ++r) { ee[mi][r] = __expf(logit[mi][r] - mx); se += ee[mi][r]; }
    se += __shfl_xor(se, 16); se += __shfl_xor(se, 32);
    const float sinv = __builtin_amdgcn_rcpf(se);
    float c0a = 0.f;
#pragma unroll
    for (int mi = 0; mi < 2; ++mi)
#pragma unroll
      for (int r = 0; r < 4; ++r) {
        uu[mi][r] = ee[mi][r] * sinv * rstd[mi][r];
        c0a += uu[mi][r] * mean[mi][r];
      }
    c0a += __shfl_xor(c0a, 16); c0a += __shfl_xor(c0a, 32);
    c0 = c0a;
  }

  // ---- pass 2: streaming pooled -> LN2 stats over this wave's 24 h-tiles ----
  float ps = 0.f, pq = 0.f, spc = 0.f;
#pragma unroll 4
  for (int j = 0; j < 24; ++j) {
    int nj = q * 24 + j;
    int h = nj * 16 + cg;
    bfrag8 vf = *(const bfrag8*)(vLds + h * 32 + rq * 8);
    bfrag8 qf = *(const bfrag8*)(qTa + (size_t)h * 32 + rq * 8);
    float pp = 0.f;
#pragma unroll
    for (int mi = 0; mi < 2; ++mi) {
      f32x4 zz = {0.f, 0.f, 0.f, 0.f};
      f32x4 pr = __builtin_amdgcn_mfma_f32_16x16x32_bf16(af[mi], vf, zz, 0, 0, 0);
      f32x4 x4 = __builtin_amdgcn_mfma_f32_16x16x32_bf16(afI[mi], qf, pr, 0, 0, 0);
#pragma unroll
      for (int r = 0; r < 4; ++r) pp += uu[mi][r] * x4[r];
    }
    pp += __shfl_xor(pp, 16); pp += __shfl_xor(pp, 32);
    float pooled = ln1_g[h] * (pp - c0) + ln1_b[h];
    ps += pooled; pq += pooled * pooled;
    spc += pooled * (ln2_g[h] * gabg[h]);
  }
  ps = sum16(ps); pq = sum16(pq); spc = sum16(spc);
  // combine with partner (disjoint xch region [768, 792))
  if (l == 0) {
    xch[768 + w * 3 + 0] = ps;
    xch[768 + w * 3 + 1] = pq;
    xch[768 + w * 3 + 2] = spc;
  }
  __syncthreads();
  {
    const int pw = w ^ 1;
    ps += xch[768 + pw * 3 + 0];
    pq += xch[768 + pw * 3 + 1];
    spc += xch[768 + pw * 3 + 2];
  }
  const float m2 = ps * (1.0f / 768.0f);
  const float var2 = pq * (1.0f / 768.0f) - m2 * m2;
  const float rs2 = rsqrtf(var2 + 1e-5f);
  const float* ea = entity_cls + (size_t)a_g * 768;
  const float* mb = mention_cls + (size_t)b_g * 768;
  float sg = 0.f;
#pragma unroll
  for (int u = 0; u < 12; ++u) sg += mb[l * 12 + u] * ea[l * 12 + u];
  sg = sum16(sg);
  sg += __shfl_xor(sg, 16); sg += __shfl_xor(sg, 32);
  float tot = rs2 * (spc - m2 * sga_f) + sba_f + sg;
  if (l == 0 && q == 0) out[b_g * 32 + a_g] = 0.5f * tot;
}

extern "C" void kernel_launch(void* const* d_in, const int* in_sizes, int n_in,
                              void* d_out, int out_size, void* d_ws, size_t ws_size,
                              hipStream_t stream) {
  const float* entity_cls     = (const float*)d_in[0];
  const float* entity_tokens  = (const float*)d_in[1];
  const float* mention_cls    = (const float*)d_in[2];
  const float* mention_tokens = (const float*)d_in[3];
  const float* Wq = (const float*)d_in[4];   const float* bq = (const float*)d_in[5];
  const float* Wk = (const float*)d_in[6];   const float* bk = (const float*)d_in[7];
  const float* Wv = (const float*)d_in[8];   const float* bv = (const float*)d_in[9];
  const float* ln1_g = (const float*)d_in[10]; const float* ln1_b = (const float*)d_in[11];
  const float* Wcls = (const float*)d_in[12];  const float* bcls = (const float*)d_in[13];
  const float* Wsp = (const float*)d_in[14];   const float* bsp = (const float*)d_in[15];
  const float* ln2_g = (const float*)d_in[16]; const float* ln2_b = (const float*)d_in[17];
  float* out = (float*)d_out;

  float* ws     = (float*)d_ws;
  float* ecls   = ws;                          // 32*768
  float* iq_sq  = ecls + 24576;                // 1024
  float* ik_sq  = iq_sq + 1024;                // 2048
  // (aux region retained for layout compatibility; unused now)
  unsigned short* qb = (unsigned short*)(ws + 55168);     // 1024*768
  unsigned short* qT = qb + 786432;                       // 32*768*32
  unsigned short* kb = qT + 786432;                       // 2048*768
  unsigned short* vT = kb + 1572864;                      // 64*768*32
  char* R = (char*)(vT + 1572864);
  unsigned short* Ae    = (unsigned short*)R;
  unsigned short* Am    = Ae + 786432;
  unsigned short* Acls  = Am + 1572864;
  unsigned short* WqT   = Acls + 24576;
  unsigned short* WkT   = WqT + 589824;
  unsigned short* WvT   = WkT + 589824;
  unsigned short* WclsT = WvT + 589824;

  prep_kernel<<<dim3(4635), dim3(256), 0, stream>>>(
      entity_tokens, mention_tokens, entity_cls, Ae, Am, Acls, iq_sq,
      Wq, Wk, Wv, Wcls, WqT, WkT, WvT, WclsT);
  proj_gemm_kernel<<<dim3(6, 16, 4), dim3(512), 0, stream>>>(
      Ae, Am, Acls, WqT, WkT, WvT, WclsT, bq, bk, bv, bcls,
      qb, qT, kb, vT, ecls, iq_sq, ik_sq);
  cos_attn_kernel<<<dim3(64, 8), dim3(512), 0, stream>>>(
      qb, kb, iq_sq, ik_sq, qT, vT,
      ln1_g, ln1_b, Wsp, bsp, ln2_g, ln2_b,
      ecls, entity_cls, mention_cls, out);
}

// Round 8
// 163.467 us; speedup vs baseline: 1.1558x; 1.0660x over previous
//
#include <hip/hip_runtime.h>
#include <math.h>

// Shapes (fixed): Na=32, La=32, B=64, Lb=32, Din=H=768.

typedef __attribute__((ext_vector_type(8))) short bfrag8;   // 8 bf16 in 4 VGPRs
typedef __attribute__((ext_vector_type(4))) float f32x4;

__device__ __forceinline__ unsigned short f2bf(float x) {
  union { float f; unsigned u; } v; v.f = x;
  unsigned r = v.u + 0x7fffu + ((v.u >> 16) & 1u);
  return (unsigned short)(r >> 16);
}

// DPP-based add-reduction over 16-lane rows (VALU pipe; avoids ds_swizzle latency).
template <int CTRL>
__device__ __forceinline__ float dpp_add(float x) {
  union { float f; int i; } a, b;
  a.f = x;
  b.i = __builtin_amdgcn_update_dpp(0, a.i, CTRL, 0xf, 0xf, true);
  return x + b.f;
}
// full sum over the 16 lanes of a DPP row (cg dimension), result in all 16 lanes
__device__ __forceinline__ float sum16(float x) {
  x = dpp_add<0xB1>(x);    // quad_perm [1,0,3,2]  : xor 1
  x = dpp_add<0x4E>(x);    // quad_perm [2,3,0,1]  : xor 2
  x = dpp_add<0x124>(x);   // row_ror:4
  x = dpp_add<0x128>(x);   // row_ror:8
  return x;
}

// ---------------- prep: casts (3 tensors) + zero norm buffer + 4 weight transposes -------------
__global__ __launch_bounds__(256) void prep_kernel(
    const float* __restrict__ a0, const float* __restrict__ a1, const float* __restrict__ a2,
    unsigned short* __restrict__ o0, unsigned short* __restrict__ o1, unsigned short* __restrict__ o2,
    float* __restrict__ nrm,
    const float* __restrict__ W0, const float* __restrict__ W1,
    const float* __restrict__ W2, const float* __restrict__ W3,
    unsigned short* __restrict__ T0, unsigned short* __restrict__ T1,
    unsigned short* __restrict__ T2, unsigned short* __restrict__ T3) {
  __shared__ float t[32][33];
  int bx = blockIdx.x;
  if (bx < 2331) {
    if (bx < 2328) {
      const float* in; unsigned short* out; int i, n4;
      if (bx < 768)       { in = a0; out = o0; i = bx * 256 + threadIdx.x;          n4 = 196608; }
      else if (bx < 2304) { in = a1; out = o1; i = (bx - 768) * 256 + threadIdx.x;  n4 = 393216; }
      else                { in = a2; out = o2; i = (bx - 2304) * 256 + threadIdx.x; n4 = 6144; }
      if (i >= n4) return;
      float4 f = ((const float4*)in)[i];
      ushort4 o;
      o.x = f2bf(f.x); o.y = f2bf(f.y); o.z = f2bf(f.z); o.w = f2bf(f.w);
      ((ushort4*)out)[i] = o;
    } else {
      int i = (bx - 2328) * 256 + threadIdx.x;
      if (i < 768) ((float4*)nrm)[i] = make_float4(0.f, 0.f, 0.f, 0.f);
    }
    return;
  }
  int idx = bx - 2331;
  int z = idx / 576, r2 = idx % 576;
  int tby = r2 / 24, tbx = r2 % 24;
  const float* W = (z == 0) ? W0 : (z == 1) ? W1 : (z == 2) ? W2 : W3;
  unsigned short* O = (z == 0) ? T0 : (z == 1) ? T1 : (z == 2) ? T2 : T3;
  const int gx = tbx * 32, gy = tby * 32;
  const int tx = threadIdx.x & 31, ty = threadIdx.x >> 5;
#pragma unroll
  for (int u = 0; u < 4; ++u) {
    int row = ty + u * 8;
    t[row][tx] = W[(size_t)(gy + row) * 768 + gx + tx];
  }
  __syncthreads();
#pragma unroll
  for (int u = 0; u < 4; ++u) {
    int row = ty + u * 8;
    O[(size_t)(gx + row) * 768 + gy + tx] = f2bf(t[tx][row]);
  }
}

// ---------------- projections, 128x64 tiles, 8 waves, ~2 blocks/CU ---------------------------
// z=0:q->qb+qT(+iq_sq), 1:k->kb(+ik_sq), 2:v->vT, 3:ecls
__global__ __launch_bounds__(512, 2) void proj_gemm_kernel(
    const unsigned short* __restrict__ Ae, const unsigned short* __restrict__ Am,
    const unsigned short* __restrict__ Acls,
    const unsigned short* __restrict__ WqT, const unsigned short* __restrict__ WkT,
    const unsigned short* __restrict__ WvT, const unsigned short* __restrict__ WclsT,
    const float* __restrict__ bq, const float* __restrict__ bk,
    const float* __restrict__ bv, const float* __restrict__ bcls,
    unsigned short* __restrict__ qb, unsigned short* __restrict__ qT,
    unsigned short* __restrict__ kb, unsigned short* __restrict__ vT,
    float* __restrict__ ecls, float* __restrict__ iq_sq, float* __restrict__ ik_sq) {
  const int z = blockIdx.z;
  const int M = (z == 0) ? 1024 : (z == 3) ? 32 : 2048;
  const int bm = blockIdx.y * 128;
  if (bm >= M) return;
  const unsigned short* A = (z == 3) ? Acls : (z == 0) ? Ae : Am;
  const unsigned short* B = (z == 0) ? WqT : (z == 1) ? WkT : (z == 2) ? WvT : WclsT;
  const float* bias = (z == 0) ? bq : (z == 1) ? bk : (z == 2) ? bv : bcls;

  __shared__ unsigned short As[128 * 64];
  __shared__ unsigned short Bs[64 * 64];
  const int t = threadIdx.x;
  const int bn = blockIdx.x * 64;
  const int l = t & 63, w = t >> 6;        // 8 waves
  const int wm = w & 3, wn = w >> 2;       // 4 row strips (32) x 2 col strips (32)
  const int cg = l & 15, rq = l >> 4;

  f32x4 acc[2][2];
#pragma unroll
  for (int mi = 0; mi < 2; ++mi)
#pragma unroll
    for (int nj = 0; nj < 2; ++nj) { f32x4 zz = {0.f, 0.f, 0.f, 0.f}; acc[mi][nj] = zz; }

  for (int k0 = 0; k0 < 768; k0 += 64) {
    __syncthreads();
#pragma unroll
    for (int u = 0; u < 2; ++u) {
      int c = t + u * 512;
      int row = c >> 3, kc = c & 7;
      int gm = bm + row; gm = gm < M ? gm : M - 1;
      int4 av = *(const int4*)(A + (size_t)gm * 768 + k0 + kc * 8);
      *(int4*)(As + row * 64 + ((kc ^ (row & 7)) * 8)) = av;
    }
    {
      int row = t >> 3, kc = t & 7;
      int4 bv4 = *(const int4*)(B + (size_t)(bn + row) * 768 + k0 + kc * 8);
      *(int4*)(Bs + row * 64 + ((kc ^ (row & 7)) * 8)) = bv4;
    }
    __syncthreads();
#pragma unroll
    for (int kk = 0; kk < 2; ++kk) {
      bfrag8 af[2], bf[2];
      const int kc = kk * 4 + rq;
#pragma unroll
      for (int mi = 0; mi < 2; ++mi) {
        int arow = wm * 32 + mi * 16 + cg;
        af[mi] = *(const bfrag8*)(As + arow * 64 + ((kc ^ (arow & 7)) * 8));
      }
#pragma unroll
      for (int nj = 0; nj < 2; ++nj) {
        int brow = wn * 32 + nj * 16 + cg;
        bf[nj] = *(const bfrag8*)(Bs + brow * 64 + ((kc ^ (brow & 7)) * 8));
      }
#pragma unroll
      for (int mi = 0; mi < 2; ++mi)
#pragma unroll
        for (int nj = 0; nj < 2; ++nj)
          acc[mi][nj] = __builtin_amdgcn_mfma_f32_16x16x32_bf16(af[mi], bf[nj], acc[mi][nj], 0, 0, 0);
    }
  }

  float p[2][4] = {};
#pragma unroll
  for (int mi = 0; mi < 2; ++mi) {
#pragma unroll
    for (int nj = 0; nj < 2; ++nj) {
      int gn = bn + wn * 32 + nj * 16 + cg;
      float bs = bias[gn];
#pragma unroll
      for (int r = 0; r < 4; ++r) {
        int gm = bm + wm * 32 + mi * 16 + rq * 4 + r;
        if (gm >= M) continue;
        float val = acc[mi][nj][r] + bs;
        if (z < 2) p[mi][r] += val * val;
        unsigned short bfv = f2bf(val);
        if (z == 0) {
          qb[(size_t)gm * 768 + gn] = bfv;
          int at = gm >> 5, j = gm & 31;
          qT[((size_t)at * 768 + gn) * 32 + j] = bfv;
        } else if (z == 1) kb[(size_t)gm * 768 + gn] = bfv;
        else if (z == 2) {
          int bb = gm >> 5, j = gm & 31;
          vT[((size_t)bb * 768 + gn) * 32 + j] = bfv;
        } else ecls[(size_t)gm * 768 + gn] = val;
      }
    }
  }
  if (z < 2) {
    float* nrm = (z == 0) ? iq_sq : ik_sq;
#pragma unroll
    for (int mi = 0; mi < 2; ++mi)
#pragma unroll
      for (int r = 0; r < 4; ++r) {
        float s = sum16(p[mi][r]);
        if (cg == 0) {
          int gm = bm + wm * 32 + mi * 16 + rq * 4 + r;
          atomicAdd(&nrm[gm], s);
        }
      }
  }
}

// ---------------- fused cos_sink + attn, 8 waves: 1 (a,b) pair per wave (R3 best config) -----
// grid (32, 8): x = b-pair (bn=x*64), y = a-group (bm=y*128). 256 blocks = 1/CU, 2 waves/SIMD.
__global__ __launch_bounds__(512, 2) void cos_attn_kernel(
    const unsigned short* __restrict__ qb, const unsigned short* __restrict__ kb,
    const float* __restrict__ iq_sq, const float* __restrict__ ik_sq,
    const unsigned short* __restrict__ qT,  // [32][768][32]
    const unsigned short* __restrict__ vT,  // [64][768][32]
    const float* __restrict__ ln1_g, const float* __restrict__ ln1_b,
    const float* __restrict__ Wsp, const float* __restrict__ bsp,
    const float* __restrict__ ln2_g, const float* __restrict__ ln2_b,
    const float* __restrict__ ecls,
    const float* __restrict__ entity_cls, const float* __restrict__ mention_cls,
    float* __restrict__ out) {
  __shared__ unsigned short vLds[2 * 768 * 32];            // 96 KB  [b_local][h][lb]
  __shared__ __align__(16) unsigned short scratch[12288];  // 24 KB: As(16K)+Bs(8K), reused as Tlds(16K)
  __shared__ float gabLds[4 * 768];                        // 12 KB  ln2_g*ecls[a_local]
  __shared__ float gwLds[768];                             // 3 KB   ln1_g*Wsp
  __shared__ float ldsIq[128], ldsIk[64];
  __shared__ float red[80];                                // 8 waves x 10 coefficient partials

  unsigned short* As = scratch;              // [128*64]
  unsigned short* Bs = scratch + 8192;       // [64*64]
  unsigned short* Tlds = scratch;            // [8 pairs][32][32], alive after GEMM only

  const int t = threadIdx.x;
  const int l = t & 63, w = t >> 6;          // w in 0..7
  const int bm = blockIdx.y * 128, bn = blockIdx.x * 64;
  const int wm = w & 3, wn = w >> 2;         // GEMM: 4 row strips x 2 col strips of 32
  const int cg = l & 15, rq = l >> 4;

  // ---- phase 0: per-block coefficient partials (visibility via first k-loop barrier) ----
  {
    float sgw = 0.f, sbw = 0.f, sga[4] = {}, sba[4] = {};
    for (int h = t; h < 768; h += 512) {
      float g1 = ln1_g[h], b1 = ln1_b[h], wsp = Wsp[h];
      float g2 = ln2_g[h], b2 = ln2_b[h];
      float gw = g1 * wsp;
      gwLds[h] = gw;
      sgw += gw; sbw += b1 * wsp;
#pragma unroll
      for (int aa = 0; aa < 4; ++aa) {
        float ec = ecls[(size_t)((blockIdx.y << 2) + aa) * 768 + h];
        float gab = g2 * ec;
        gabLds[aa * 768 + h] = gab;
        sga[aa] += gab; sba[aa] += b2 * ec;
      }
    }
    sgw = sum16(sgw); sbw = sum16(sbw);
#pragma unroll
    for (int aa = 0; aa < 4; ++aa) { sga[aa] = sum16(sga[aa]); sba[aa] = sum16(sba[aa]); }
#pragma unroll
    for (int m = 16; m < 64; m <<= 1) {
      sgw += __shfl_xor(sgw, m); sbw += __shfl_xor(sbw, m);
#pragma unroll
      for (int aa = 0; aa < 4; ++aa) { sga[aa] += __shfl_xor(sga[aa], m); sba[aa] += __shfl_xor(sba[aa], m); }
    }
    if (l == 0) {
      red[w * 10 + 0] = sgw; red[w * 10 + 1] = sbw;
#pragma unroll
      for (int aa = 0; aa < 4; ++aa) { red[w * 10 + 2 + aa] = sga[aa]; red[w * 10 + 6 + aa] = sba[aa]; }
    }
  }
  if (t < 128) ldsIq[t] = iq_sq[bm + t];
  else if (t < 192) ldsIk[t - 128] = ik_sq[bn + t - 128];

  // ---- phase 1: cos GEMM (32x32 per wave) + vT->LDS copy interleaved ----
  const int4* vsrc = (const int4*)(vT + (size_t)(blockIdx.x * 2) * 768 * 32);
  int4* vdst = (int4*)vLds;

  f32x4 acc[2][2];
#pragma unroll
  for (int mi = 0; mi < 2; ++mi)
#pragma unroll
    for (int nj = 0; nj < 2; ++nj) { f32x4 zz = {0.f, 0.f, 0.f, 0.f}; acc[mi][nj] = zz; }

  for (int k0 = 0, s = 0; k0 < 768; k0 += 64, ++s) {
    __syncthreads();
#pragma unroll
    for (int u = 0; u < 2; ++u) {
      int c = t + u * 512;
      int row = c >> 3, kc = c & 7;
      int4 av = *(const int4*)(qb + (size_t)(bm + row) * 768 + k0 + kc * 8);
      *(int4*)(As + row * 64 + ((kc ^ (row & 7)) * 8)) = av;
    }
    {
      int row = t >> 3, kc = t & 7;
      int4 bv4 = *(const int4*)(kb + (size_t)(bn + row) * 768 + k0 + kc * 8);
      *(int4*)(Bs + row * 64 + ((kc ^ (row & 7)) * 8)) = bv4;
    }
    vdst[t + s * 512] = vsrc[t + s * 512];
    __syncthreads();
#pragma unroll
    for (int kk = 0; kk < 2; ++kk) {
      bfrag8 af[2], bf[2];
      const int kc = kk * 4 + rq;
#pragma unroll
      for (int mi = 0; mi < 2; ++mi) {
        int arow = wm * 32 + mi * 16 + cg;
        af[mi] = *(const bfrag8*)(As + arow * 64 + ((kc ^ (arow & 7)) * 8));
      }
#pragma unroll
      for (int nj = 0; nj < 2; ++nj) {
        int brow = wn * 32 + nj * 16 + cg;
        bf[nj] = *(const bfrag8*)(Bs + brow * 64 + ((kc ^ (brow & 7)) * 8));
      }
#pragma unroll
      for (int mi = 0; mi < 2; ++mi)
#pragma unroll
        for (int nj = 0; nj < 2; ++nj)
          acc[mi][nj] = __builtin_amdgcn_mfma_f32_16x16x32_bf16(af[mi], bf[nj], acc[mi][nj], 0, 0, 0);
    }
  }

  // ---- phase 2: cosine normalize, exp, Sinkhorn, L2-row-normalize (one 32x32 pair) ----
  float irow[2][4], icol[2];
#pragma unroll
  for (int mi = 0; mi < 2; ++mi)
#pragma unroll
    for (int r = 0; r < 4; ++r) {
      float sv = ldsIq[wm * 32 + mi * 16 + rq * 4 + r];
      irow[mi][r] = 1.0f / fmaxf(sqrtf(sv), 1e-8f);
    }
#pragma unroll
  for (int nj = 0; nj < 2; ++nj) {
    float sv = ldsIk[wn * 32 + nj * 16 + cg];
    icol[nj] = 1.0f / fmaxf(sqrtf(sv), 1e-8f);
  }
#pragma unroll
  for (int mi = 0; mi < 2; ++mi)
#pragma unroll
    for (int nj = 0; nj < 2; ++nj)
#pragma unroll
      for (int r = 0; r < 4; ++r)
        acc[mi][nj][r] = __expf(acc[mi][nj][r] * irow[mi][r] * icol[nj] * 10.0f);

  for (int it = 0; it < 10; ++it) {
#pragma unroll
    for (int mi = 0; mi < 2; ++mi)
#pragma unroll
      for (int r = 0; r < 4; ++r) {
        float rs = sum16(acc[mi][0][r] + acc[mi][1][r]);
        float rinv = __builtin_amdgcn_rcpf(rs);
        acc[mi][0][r] *= rinv; acc[mi][1][r] *= rinv;
      }
#pragma unroll
    for (int nj = 0; nj < 2; ++nj) {
      float cs = acc[0][nj][0] + acc[0][nj][1] + acc[0][nj][2] + acc[0][nj][3]
               + acc[1][nj][0] + acc[1][nj][1] + acc[1][nj][2] + acc[1][nj][3];
      cs += __shfl_xor(cs, 16); cs += __shfl_xor(cs, 32);
      float cinv = __builtin_amdgcn_rcpf(cs);
#pragma unroll
      for (int mi = 0; mi < 2; ++mi)
#pragma unroll
        for (int r = 0; r < 4; ++r) acc[mi][nj][r] *= cinv;
    }
  }

#pragma unroll
  for (int mi = 0; mi < 2; ++mi)
#pragma unroll
    for (int r = 0; r < 4; ++r) {
      float ss = sum16(acc[mi][0][r] * acc[mi][0][r] + acc[mi][1][r] * acc[mi][1][r]);
      float tinv = 1.0f / fmaxf(sqrtf(ss), 1e-12f);
      acc[mi][0][r] *= tinv; acc[mi][1][r] *= tinv;
    }

  // ---- phase 3: T -> LDS (aliases dead As/Bs; barrier on both sides) ----
  __syncthreads();   // all waves past their last As/Bs fragment read
  {
    unsigned short* base = Tlds + ((wn * 4 + wm) << 10);   // pair index b_loc*4 + a_loc
#pragma unroll
    for (int mi = 0; mi < 2; ++mi)
#pragma unroll
      for (int nj = 0; nj < 2; ++nj)
#pragma unroll
        for (int r = 0; r < 4; ++r)
          base[(mi * 16 + rq * 4 + r) * 32 + nj * 16 + cg] = f2bf(acc[mi][nj][r]);
  }
  __syncthreads();   // Tlds + vLds ready for everyone

  // ---- phase 4: attention. wave w: b_local = w&1, a_local = w>>1 (one combo each) ----
  const int bl = w & 1, ah = w >> 1;
  const int b_g = (blockIdx.x << 1) + bl;
  const int a_g = (blockIdx.y << 2) + ah;
  const unsigned short* vbase = vLds + bl * 24576;

  float sgw_f = 0.f, sbw_f = 0.f, sga_f = 0.f, sba_f = 0.f;
#pragma unroll
  for (int wv = 0; wv < 8; ++wv) {
    sgw_f += red[wv * 10 + 0]; sbw_f += red[wv * 10 + 1];
    sga_f += red[wv * 10 + 2 + ah]; sba_f += red[wv * 10 + 6 + ah];
  }
  sbw_f += bsp[0];

  const unsigned short* qTa = qT + (size_t)a_g * 24576;
  const unsigned short* Tp = Tlds + ((bl * 4 + ah) << 10);
  bfrag8 af[2], afI[2];
#pragma unroll
  for (int mi = 0; mi < 2; ++mi) {
    af[mi] = *(const bfrag8*)(Tp + (mi * 16 + cg) * 32 + rq * 8);
    int row = mi * 16 + cg;
    bfrag8 fI;
#pragma unroll
    for (int u = 0; u < 8; ++u) fI[u] = (row == rq * 8 + u) ? (short)0x3F80 : (short)0;
    afI[mi] = fI;
  }

  // ---- pass 1: row stats ----
  float s1[2][4] = {}, s2[2][4] = {}, a1[2][4] = {};
#pragma unroll 4
  for (int nj = 0; nj < 48; ++nj) {
    int h = nj * 16 + cg;
    bfrag8 vf = *(const bfrag8*)(vbase + h * 32 + rq * 8);
    bfrag8 qf = *(const bfrag8*)(qTa + (size_t)h * 32 + rq * 8);
    float gw = gwLds[h];
#pragma unroll
    for (int mi = 0; mi < 2; ++mi) {
      f32x4 zz = {0.f, 0.f, 0.f, 0.f};
      f32x4 p = __builtin_amdgcn_mfma_f32_16x16x32_bf16(af[mi], vf, zz, 0, 0, 0);
      f32x4 x4 = __builtin_amdgcn_mfma_f32_16x16x32_bf16(afI[mi], qf, p, 0, 0, 0);
#pragma unroll
      for (int r = 0; r < 4; ++r) {
        float x = x4[r];
        s1[mi][r] += x; s2[mi][r] += x * x; a1[mi][r] += x * gw;
      }
    }
  }
#pragma unroll
  for (int mi = 0; mi < 2; ++mi)
#pragma unroll
    for (int r = 0; r < 4; ++r) {
      s1[mi][r] = sum16(s1[mi][r]);
      s2[mi][r] = sum16(s2[mi][r]);
      a1[mi][r] = sum16(a1[mi][r]);
    }

  // ---- logits, softmax, u, c0 ----
  float uu[2][4], c0;
  {
    float mean[2][4], rstd[2][4], logit[2][4];
#pragma unroll
    for (int mi = 0; mi < 2; ++mi)
#pragma unroll
      for (int r = 0; r < 4; ++r) {
        float m1 = s1[mi][r] * (1.0f / 768.0f);
        float var = s2[mi][r] * (1.0f / 768.0f) - m1 * m1;
        float rs = rsqrtf(var + 1e-5f);
        mean[mi][r] = m1; rstd[mi][r] = rs;
        logit[mi][r] = rs * (a1[mi][r] - m1 * sgw_f) + sbw_f;
      }
    float mx = logit[0][0];
#pragma unroll
    for (int mi = 0; mi < 2; ++mi)
#pragma unroll
      for (int r = 0; r < 4; ++r) mx = fmaxf(mx, logit[mi][r]);
    mx = fmaxf(mx, __shfl_xor(mx, 16)); mx = fmaxf(mx, __shfl_xor(mx, 32));
    float se = 0.f, ee[2][4];
#pragma unroll
    for (int mi = 0; mi < 2; ++mi)
#pragma unroll
      for (int r = 0; r < 4; ++r) { ee[mi][r] = __expf(logit[mi][r] - mx); se += ee[mi][r]; }
    se += __shfl_xor(se, 16); se += __shfl_xor(se, 32);
    const float sinv = __builtin_amdgcn_rcpf(se);
    float c0a = 0.f;
#pragma unroll
    for (int mi = 0; mi < 2; ++mi)
#pragma unroll
      for (int r = 0; r < 4; ++r) {
        uu[mi][r] = ee[mi][r] * sinv * rstd[mi][r];
        c0a += uu[mi][r] * mean[mi][r];
      }
    c0a += __shfl_xor(c0a, 16); c0a += __shfl_xor(c0a, 32);
    c0 = c0a;
  }

  // ---- pass 2: streaming pooled -> LN2 stats ----
  float ps = 0.f, pq = 0.f, spc = 0.f;
#pragma unroll 4
  for (int nj = 0; nj < 48; ++nj) {
    int h = nj * 16 + cg;
    bfrag8 vf = *(const bfrag8*)(vbase + h * 32 + rq * 8);
    bfrag8 qf = *(const bfrag8*)(qTa + (size_t)h * 32 + rq * 8);
    float pp = 0.f;
#pragma unroll
    for (int mi = 0; mi < 2; ++mi) {
      f32x4 zz = {0.f, 0.f, 0.f, 0.f};
      f32x4 p = __builtin_amdgcn_mfma_f32_16x16x32_bf16(af[mi], vf, zz, 0, 0, 0);
      f32x4 x4 = __builtin_amdgcn_mfma_f32_16x16x32_bf16(afI[mi], qf, p, 0, 0, 0);
#pragma unroll
      for (int r = 0; r < 4; ++r) pp += uu[mi][r] * x4[r];
    }
    pp += __shfl_xor(pp, 16); pp += __shfl_xor(pp, 32);
    float pooled = ln1_g[h] * (pp - c0) + ln1_b[h];
    ps += pooled; pq += pooled * pooled;
    spc += pooled * gabLds[ah * 768 + h];
  }
  ps = sum16(ps); pq = sum16(pq); spc = sum16(spc);
  const float m2 = ps * (1.0f / 768.0f);
  const float var2 = pq * (1.0f / 768.0f) - m2 * m2;
  const float rs2 = rsqrtf(var2 + 1e-5f);
  const float* ea = entity_cls + (size_t)a_g * 768;
  const float* mb = mention_cls + (size_t)b_g * 768;
  float sg = 0.f;
#pragma unroll
  for (int u = 0; u < 12; ++u) sg += mb[l * 12 + u] * ea[l * 12 + u];
  sg = sum16(sg);
  sg += __shfl_xor(sg, 16); sg += __shfl_xor(sg, 32);
  float tot = rs2 * (spc - m2 * sga_f) + sba_f + sg;
  if (l == 0) out[b_g * 32 + a_g] = 0.5f * tot;
}

extern "C" void kernel_launch(void* const* d_in, const int* in_sizes, int n_in,
                              void* d_out, int out_size, void* d_ws, size_t ws_size,
                              hipStream_t stream) {
  const float* entity_cls     = (const float*)d_in[0];
  const float* entity_tokens  = (const float*)d_in[1];
  const float* mention_cls    = (const float*)d_in[2];
  const float* mention_tokens = (const float*)d_in[3];
  const float* Wq = (const float*)d_in[4];   const float* bq = (const float*)d_in[5];
  const float* Wk = (const float*)d_in[6];   const float* bk = (const float*)d_in[7];
  const float* Wv = (const float*)d_in[8];   const float* bv = (const float*)d_in[9];
  const float* ln1_g = (const float*)d_in[10]; const float* ln1_b = (const float*)d_in[11];
  const float* Wcls = (const float*)d_in[12];  const float* bcls = (const float*)d_in[13];
  const float* Wsp = (const float*)d_in[14];   const float* bsp = (const float*)d_in[15];
  const float* ln2_g = (const float*)d_in[16]; const float* ln2_b = (const float*)d_in[17];
  float* out = (float*)d_out;

  float* ws     = (float*)d_ws;
  float* ecls   = ws;                          // 32*768
  float* iq_sq  = ecls + 24576;                // 1024
  float* ik_sq  = iq_sq + 1024;                // 2048
  // (aux region retained for layout compatibility; unused now)
  unsigned short* qb = (unsigned short*)(ws + 55168);     // 1024*768
  unsigned short* qT = qb + 786432;                       // 32*768*32
  unsigned short* kb = qT + 786432;                       // 2048*768
  unsigned short* vT = kb + 1572864;                      // 64*768*32
  char* R = (char*)(vT + 1572864);
  unsigned short* Ae    = (unsigned short*)R;
  unsigned short* Am    = Ae + 786432;
  unsigned short* Acls  = Am + 1572864;
  unsigned short* WqT   = Acls + 24576;
  unsigned short* WkT   = WqT + 589824;
  unsigned short* WvT   = WkT + 589824;
  unsigned short* WclsT = WvT + 589824;

  prep_kernel<<<dim3(4635), dim3(256), 0, stream>>>(
      entity_tokens, mention_tokens, entity_cls, Ae, Am, Acls, iq_sq,
      Wq, Wk, Wv, Wcls, WqT, WkT, WvT, WclsT);
  proj_gemm_kernel<<<dim3(12, 16, 4), dim3(512), 0, stream>>>(
      Ae, Am, Acls, WqT, WkT, WvT, WclsT, bq, bk, bv, bcls,
      qb, qT, kb, vT, ecls, iq_sq, ik_sq);
  cos_attn_kernel<<<dim3(32, 8), dim3(512), 0, stream>>>(
      qb, kb, iq_sq, ik_sq, qT, vT,
      ln1_g, ln1_b, Wsp, bsp, ln2_g, ln2_b,
      ecls, entity_cls, mention_cls, out);
}

// Round 9
// 162.953 us; speedup vs baseline: 1.1595x; 1.0031x over previous
//
#include <hip/hip_runtime.h>
#include <math.h>

// Shapes (fixed): Na=32, La=32, B=64, Lb=32, Din=H=768.

typedef __attribute__((ext_vector_type(8))) short bfrag8;   // 8 bf16 in 4 VGPRs
typedef __attribute__((ext_vector_type(4))) float f32x4;

__device__ __forceinline__ unsigned short f2bf(float x) {
  union { float f; unsigned u; } v; v.f = x;
  unsigned r = v.u + 0x7fffu + ((v.u >> 16) & 1u);
  return (unsigned short)(r >> 16);
}
__device__ __forceinline__ float bf2f(unsigned short x) {
  union { float f; unsigned u; } v; v.u = ((unsigned)x) << 16; return v.f;
}

// DPP-based add-reduction over 16-lane rows (VALU pipe; avoids ds_swizzle latency).
template <int CTRL>
__device__ __forceinline__ float dpp_add(float x) {
  union { float f; int i; } a, b;
  a.f = x;
  b.i = __builtin_amdgcn_update_dpp(0, a.i, CTRL, 0xf, 0xf, true);
  return x + b.f;
}
// full sum over the 16 lanes of a DPP row (cg dimension), result in all 16 lanes
__device__ __forceinline__ float sum16(float x) {
  x = dpp_add<0xB1>(x);    // quad_perm [1,0,3,2]  : xor 1
  x = dpp_add<0x4E>(x);    // quad_perm [2,3,0,1]  : xor 2
  x = dpp_add<0x124>(x);   // row_ror:4
  x = dpp_add<0x128>(x);   // row_ror:8
  return x;
}

// ---------------- prep: casts (3 tensors) + zero norm buffer + 4 weight transposes -------------
__global__ __launch_bounds__(256) void prep_kernel(
    const float* __restrict__ a0, const float* __restrict__ a1, const float* __restrict__ a2,
    unsigned short* __restrict__ o0, unsigned short* __restrict__ o1, unsigned short* __restrict__ o2,
    float* __restrict__ nrm,
    const float* __restrict__ W0, const float* __restrict__ W1,
    const float* __restrict__ W2, const float* __restrict__ W3,
    unsigned short* __restrict__ T0, unsigned short* __restrict__ T1,
    unsigned short* __restrict__ T2, unsigned short* __restrict__ T3) {
  __shared__ float t[32][33];
  int bx = blockIdx.x;
  if (bx < 2331) {
    if (bx < 2328) {
      const float* in; unsigned short* out; int i, n4;
      if (bx < 768)       { in = a0; out = o0; i = bx * 256 + threadIdx.x;          n4 = 196608; }
      else if (bx < 2304) { in = a1; out = o1; i = (bx - 768) * 256 + threadIdx.x;  n4 = 393216; }
      else                { in = a2; out = o2; i = (bx - 2304) * 256 + threadIdx.x; n4 = 6144; }
      if (i >= n4) return;
      float4 f = ((const float4*)in)[i];
      ushort4 o;
      o.x = f2bf(f.x); o.y = f2bf(f.y); o.z = f2bf(f.z); o.w = f2bf(f.w);
      ((ushort4*)out)[i] = o;
    } else {
      int i = (bx - 2328) * 256 + threadIdx.x;
      if (i < 768) ((float4*)nrm)[i] = make_float4(0.f, 0.f, 0.f, 0.f);
    }
    return;
  }
  int idx = bx - 2331;
  int z = idx / 576, r2 = idx % 576;
  int tby = r2 / 24, tbx = r2 % 24;
  const float* W = (z == 0) ? W0 : (z == 1) ? W1 : (z == 2) ? W2 : W3;
  unsigned short* O = (z == 0) ? T0 : (z == 1) ? T1 : (z == 2) ? T2 : T3;
  const int gx = tbx * 32, gy = tby * 32;
  const int tx = threadIdx.x & 31, ty = threadIdx.x >> 5;
#pragma unroll
  for (int u = 0; u < 4; ++u) {
    int row = ty + u * 8;
    t[row][tx] = W[(size_t)(gy + row) * 768 + gx + tx];
  }
  __syncthreads();
#pragma unroll
  for (int u = 0; u < 4; ++u) {
    int row = ty + u * 8;
    O[(size_t)(gx + row) * 768 + gy + tx] = f2bf(t[tx][row]);
  }
}

// ---------------- projections, 128x64 tiles, 8 waves, ~2 blocks/CU ---------------------------
// z=0:q->qb+qT(+iq_sq), 1:k->kb(+ik_sq), 2:v->vT, 3:ecls
__global__ __launch_bounds__(512, 2) void proj_gemm_kernel(
    const unsigned short* __restrict__ Ae, const unsigned short* __restrict__ Am,
    const unsigned short* __restrict__ Acls,
    const unsigned short* __restrict__ WqT, const unsigned short* __restrict__ WkT,
    const unsigned short* __restrict__ WvT, const unsigned short* __restrict__ WclsT,
    const float* __restrict__ bq, const float* __restrict__ bk,
    const float* __restrict__ bv, const float* __restrict__ bcls,
    unsigned short* __restrict__ qb, unsigned short* __restrict__ qT,
    unsigned short* __restrict__ kb, unsigned short* __restrict__ vT,
    float* __restrict__ ecls, float* __restrict__ iq_sq, float* __restrict__ ik_sq) {
  const int z = blockIdx.z;
  const int M = (z == 0) ? 1024 : (z == 3) ? 32 : 2048;
  const int bm = blockIdx.y * 128;
  if (bm >= M) return;
  const unsigned short* A = (z == 3) ? Acls : (z == 0) ? Ae : Am;
  const unsigned short* B = (z == 0) ? WqT : (z == 1) ? WkT : (z == 2) ? WvT : WclsT;
  const float* bias = (z == 0) ? bq : (z == 1) ? bk : (z == 2) ? bv : bcls;

  __shared__ unsigned short As[128 * 64];
  __shared__ unsigned short Bs[64 * 64];
  const int t = threadIdx.x;
  const int bn = blockIdx.x * 64;
  const int l = t & 63, w = t >> 6;        // 8 waves
  const int wm = w & 3, wn = w >> 2;       // 4 row strips (32) x 2 col strips (32)
  const int cg = l & 15, rq = l >> 4;

  f32x4 acc[2][2];
#pragma unroll
  for (int mi = 0; mi < 2; ++mi)
#pragma unroll
    for (int nj = 0; nj < 2; ++nj) { f32x4 zz = {0.f, 0.f, 0.f, 0.f}; acc[mi][nj] = zz; }

  for (int k0 = 0; k0 < 768; k0 += 64) {
    __syncthreads();
#pragma unroll
    for (int u = 0; u < 2; ++u) {
      int c = t + u * 512;
      int row = c >> 3, kc = c & 7;
      int gm = bm + row; gm = gm < M ? gm : M - 1;
      int4 av = *(const int4*)(A + (size_t)gm * 768 + k0 + kc * 8);
      *(int4*)(As + row * 64 + ((kc ^ (row & 7)) * 8)) = av;
    }
    {
      int row = t >> 3, kc = t & 7;
      int4 bv4 = *(const int4*)(B + (size_t)(bn + row) * 768 + k0 + kc * 8);
      *(int4*)(Bs + row * 64 + ((kc ^ (row & 7)) * 8)) = bv4;
    }
    __syncthreads();
#pragma unroll
    for (int kk = 0; kk < 2; ++kk) {
      bfrag8 af[2], bf[2];
      const int kc = kk * 4 + rq;
#pragma unroll
      for (int mi = 0; mi < 2; ++mi) {
        int arow = wm * 32 + mi * 16 + cg;
        af[mi] = *(const bfrag8*)(As + arow * 64 + ((kc ^ (arow & 7)) * 8));
      }
#pragma unroll
      for (int nj = 0; nj < 2; ++nj) {
        int brow = wn * 32 + nj * 16 + cg;
        bf[nj] = *(const bfrag8*)(Bs + brow * 64 + ((kc ^ (brow & 7)) * 8));
      }
#pragma unroll
      for (int mi = 0; mi < 2; ++mi)
#pragma unroll
        for (int nj = 0; nj < 2; ++nj)
          acc[mi][nj] = __builtin_amdgcn_mfma_f32_16x16x32_bf16(af[mi], bf[nj], acc[mi][nj], 0, 0, 0);
    }
  }

  float p[2][4] = {};
#pragma unroll
  for (int mi = 0; mi < 2; ++mi) {
#pragma unroll
    for (int nj = 0; nj < 2; ++nj) {
      int gn = bn + wn * 32 + nj * 16 + cg;
      float bs = bias[gn];
#pragma unroll
      for (int r = 0; r < 4; ++r) {
        int gm = bm + wm * 32 + mi * 16 + rq * 4 + r;
        if (gm >= M) continue;
        float val = acc[mi][nj][r] + bs;
        if (z < 2) p[mi][r] += val * val;
        unsigned short bfv = f2bf(val);
        if (z == 0) {
          qb[(size_t)gm * 768 + gn] = bfv;
          int at = gm >> 5, j = gm & 31;
          qT[((size_t)at * 768 + gn) * 32 + j] = bfv;
        } else if (z == 1) kb[(size_t)gm * 768 + gn] = bfv;
        else if (z == 2) {
          int bb = gm >> 5, j = gm & 31;
          vT[((size_t)bb * 768 + gn) * 32 + j] = bfv;
        } else ecls[(size_t)gm * 768 + gn] = val;
      }
    }
  }
  if (z < 2) {
    float* nrm = (z == 0) ? iq_sq : ik_sq;
#pragma unroll
    for (int mi = 0; mi < 2; ++mi)
#pragma unroll
      for (int r = 0; r < 4; ++r) {
        float s = sum16(p[mi][r]);
        if (cg == 0) {
          int gm = bm + wm * 32 + mi * 16 + rq * 4 + r;
          atomicAdd(&nrm[gm], s);
        }
      }
  }
}

// ---------------- fused cos_sink + attn, 8 waves: 1 (a,b) pair per wave ----------------------
// grid (32, 8): x = b-pair (bn=x*64), y = a-group (bm=y*128). 256 blocks = 1/CU, 2 waves/SIMD.
// Pass 2 uses the rank-1 identity: pooled = (u.T).V + u.q  (single-row MFMAs, no per-nj shuffles).
__global__ __launch_bounds__(512, 2) void cos_attn_kernel(
    const unsigned short* __restrict__ qb, const unsigned short* __restrict__ kb,
    const float* __restrict__ iq_sq, const float* __restrict__ ik_sq,
    const unsigned short* __restrict__ qT,  // [32][768][32]
    const unsigned short* __restrict__ vT,  // [64][768][32]
    const float* __restrict__ ln1_g, const float* __restrict__ ln1_b,
    const float* __restrict__ Wsp, const float* __restrict__ bsp,
    const float* __restrict__ ln2_g, const float* __restrict__ ln2_b,
    const float* __restrict__ ecls,
    const float* __restrict__ entity_cls, const float* __restrict__ mention_cls,
    float* __restrict__ out) {
  __shared__ unsigned short vLds[2 * 768 * 32];            // 96 KB  [b_local][h][lb]
  __shared__ __align__(16) unsigned short scratch[12288];  // 24 KB: As(16K)+Bs(8K), reused as Tlds(16K)
  __shared__ float gabLds[4 * 768];                        // 12 KB  ln2_g*ecls[a_local]
  __shared__ float gwLds[768];                             // 3 KB   ln1_g*Wsp
  __shared__ float ldsIq[128], ldsIk[64];
  __shared__ float red[80];                                // 8 waves x 10 coefficient partials
  __shared__ __align__(16) unsigned short uLds[8 * 32];    // u (bf16) per pair
  __shared__ __align__(16) unsigned short tvLds[8 * 32];   // tv = u.T (bf16) per pair

  unsigned short* As = scratch;              // [128*64]
  unsigned short* Bs = scratch + 8192;       // [64*64]
  unsigned short* Tlds = scratch;            // [8 pairs][32][32], alive after GEMM only

  const int t = threadIdx.x;
  const int l = t & 63, w = t >> 6;          // w in 0..7
  const int bm = blockIdx.y * 128, bn = blockIdx.x * 64;
  const int wm = w & 3, wn = w >> 2;         // GEMM: 4 row strips x 2 col strips of 32
  const int cg = l & 15, rq = l >> 4;

  // ---- phase 0: per-block coefficient partials (visibility via first k-loop barrier) ----
  {
    float sgw = 0.f, sbw = 0.f, sga[4] = {}, sba[4] = {};
    for (int h = t; h < 768; h += 512) {
      float g1 = ln1_g[h], b1 = ln1_b[h], wsp = Wsp[h];
      float g2 = ln2_g[h], b2 = ln2_b[h];
      float gw = g1 * wsp;
      gwLds[h] = gw;
      sgw += gw; sbw += b1 * wsp;
#pragma unroll
      for (int aa = 0; aa < 4; ++aa) {
        float ec = ecls[(size_t)((blockIdx.y << 2) + aa) * 768 + h];
        float gab = g2 * ec;
        gabLds[aa * 768 + h] = gab;
        sga[aa] += gab; sba[aa] += b2 * ec;
      }
    }
    sgw = sum16(sgw); sbw = sum16(sbw);
#pragma unroll
    for (int aa = 0; aa < 4; ++aa) { sga[aa] = sum16(sga[aa]); sba[aa] = sum16(sba[aa]); }
#pragma unroll
    for (int m = 16; m < 64; m <<= 1) {
      sgw += __shfl_xor(sgw, m); sbw += __shfl_xor(sbw, m);
#pragma unroll
      for (int aa = 0; aa < 4; ++aa) { sga[aa] += __shfl_xor(sga[aa], m); sba[aa] += __shfl_xor(sba[aa], m); }
    }
    if (l == 0) {
      red[w * 10 + 0] = sgw; red[w * 10 + 1] = sbw;
#pragma unroll
      for (int aa = 0; aa < 4; ++aa) { red[w * 10 + 2 + aa] = sga[aa]; red[w * 10 + 6 + aa] = sba[aa]; }
    }
  }
  if (t < 128) ldsIq[t] = iq_sq[bm + t];
  else if (t < 192) ldsIk[t - 128] = ik_sq[bn + t - 128];

  // ---- phase 1: cos GEMM (32x32 per wave) + vT->LDS copy interleaved ----
  const int4* vsrc = (const int4*)(vT + (size_t)(blockIdx.x * 2) * 768 * 32);
  int4* vdst = (int4*)vLds;

  f32x4 acc[2][2];
#pragma unroll
  for (int mi = 0; mi < 2; ++mi)
#pragma unroll
    for (int nj = 0; nj < 2; ++nj) { f32x4 zz = {0.f, 0.f, 0.f, 0.f}; acc[mi][nj] = zz; }

  for (int k0 = 0, s = 0; k0 < 768; k0 += 64, ++s) {
    __syncthreads();
#pragma unroll
    for (int u = 0; u < 2; ++u) {
      int c = t + u * 512;
      int row = c >> 3, kc = c & 7;
      int4 av = *(const int4*)(qb + (size_t)(bm + row) * 768 + k0 + kc * 8);
      *(int4*)(As + row * 64 + ((kc ^ (row & 7)) * 8)) = av;
    }
    {
      int row = t >> 3, kc = t & 7;
      int4 bv4 = *(const int4*)(kb + (size_t)(bn + row) * 768 + k0 + kc * 8);
      *(int4*)(Bs + row * 64 + ((kc ^ (row & 7)) * 8)) = bv4;
    }
    vdst[t + s * 512] = vsrc[t + s * 512];
    __syncthreads();
#pragma unroll
    for (int kk = 0; kk < 2; ++kk) {
      bfrag8 af[2], bf[2];
      const int kc = kk * 4 + rq;
#pragma unroll
      for (int mi = 0; mi < 2; ++mi) {
        int arow = wm * 32 + mi * 16 + cg;
        af[mi] = *(const bfrag8*)(As + arow * 64 + ((kc ^ (arow & 7)) * 8));
      }
#pragma unroll
      for (int nj = 0; nj < 2; ++nj) {
        int brow = wn * 32 + nj * 16 + cg;
        bf[nj] = *(const bfrag8*)(Bs + brow * 64 + ((kc ^ (brow & 7)) * 8));
      }
#pragma unroll
      for (int mi = 0; mi < 2; ++mi)
#pragma unroll
        for (int nj = 0; nj < 2; ++nj)
          acc[mi][nj] = __builtin_amdgcn_mfma_f32_16x16x32_bf16(af[mi], bf[nj], acc[mi][nj], 0, 0, 0);
    }
  }

  // ---- phase 2: cosine normalize, exp, Sinkhorn, L2-row-normalize (one 32x32 pair) ----
  float irow[2][4], icol[2];
#pragma unroll
  for (int mi = 0; mi < 2; ++mi)
#pragma unroll
    for (int r = 0; r < 4; ++r) {
      float sv = ldsIq[wm * 32 + mi * 16 + rq * 4 + r];
      irow[mi][r] = 1.0f / fmaxf(sqrtf(sv), 1e-8f);
    }
#pragma unroll
  for (int nj = 0; nj < 2; ++nj) {
    float sv = ldsIk[wn * 32 + nj * 16 + cg];
    icol[nj] = 1.0f / fmaxf(sqrtf(sv), 1e-8f);
  }
#pragma unroll
  for (int mi = 0; mi < 2; ++mi)
#pragma unroll
    for (int nj = 0; nj < 2; ++nj)
#pragma unroll
      for (int r = 0; r < 4; ++r)
        acc[mi][nj][r] = __expf(acc[mi][nj][r] * irow[mi][r] * icol[nj] * 10.0f);

  for (int it = 0; it < 10; ++it) {
#pragma unroll
    for (int mi = 0; mi < 2; ++mi)
#pragma unroll
      for (int r = 0; r < 4; ++r) {
        float rs = sum16(acc[mi][0][r] + acc[mi][1][r]);
        float rinv = __builtin_amdgcn_rcpf(rs);
        acc[mi][0][r] *= rinv; acc[mi][1][r] *= rinv;
      }
#pragma unroll
    for (int nj = 0; nj < 2; ++nj) {
      float cs = acc[0][nj][0] + acc[0][nj][1] + acc[0][nj][2] + acc[0][nj][3]
               + acc[1][nj][0] + acc[1][nj][1] + acc[1][nj][2] + acc[1][nj][3];
      cs += __shfl_xor(cs, 16); cs += __shfl_xor(cs, 32);
      float cinv = __builtin_amdgcn_rcpf(cs);
#pragma unroll
      for (int mi = 0; mi < 2; ++mi)
#pragma unroll
        for (int r = 0; r < 4; ++r) acc[mi][nj][r] *= cinv;
    }
  }

#pragma unroll
  for (int mi = 0; mi < 2; ++mi)
#pragma unroll
    for (int r = 0; r < 4; ++r) {
      float ss = sum16(acc[mi][0][r] * acc[mi][0][r] + acc[mi][1][r] * acc[mi][1][r]);
      float tinv = 1.0f / fmaxf(sqrtf(ss), 1e-12f);
      acc[mi][0][r] *= tinv; acc[mi][1][r] *= tinv;
    }

  // ---- phase 3: T -> LDS (aliases dead As/Bs; barrier on both sides) ----
  __syncthreads();   // all waves past their last As/Bs fragment read
  {
    unsigned short* base = Tlds + ((wn * 4 + wm) << 10);   // pair index b_loc*4 + a_loc
#pragma unroll
    for (int mi = 0; mi < 2; ++mi)
#pragma unroll
      for (int nj = 0; nj < 2; ++nj)
#pragma unroll
        for (int r = 0; r < 4; ++r)
          base[(mi * 16 + rq * 4 + r) * 32 + nj * 16 + cg] = f2bf(acc[mi][nj][r]);
  }
  __syncthreads();   // Tlds + vLds ready for everyone

  // ---- phase 4: attention. wave w: b_local = w&1, a_local = w>>1 (one combo each) ----
  const int bl = w & 1, ah = w >> 1;
  const int b_g = (blockIdx.x << 1) + bl;
  const int a_g = (blockIdx.y << 2) + ah;
  const unsigned short* vbase = vLds + bl * 24576;
  const int pairIdx = bl * 4 + ah;

  float sgw_f = 0.f, sbw_f = 0.f, sga_f = 0.f, sba_f = 0.f;
#pragma unroll
  for (int wv = 0; wv < 8; ++wv) {
    sgw_f += red[wv * 10 + 0]; sbw_f += red[wv * 10 + 1];
    sga_f += red[wv * 10 + 2 + ah]; sba_f += red[wv * 10 + 6 + ah];
  }
  sbw_f += bsp[0];

  const unsigned short* qTa = qT + (size_t)a_g * 24576;
  const unsigned short* Tp = Tlds + (pairIdx << 10);
  bfrag8 af[2], afI[2];
#pragma unroll
  for (int mi = 0; mi < 2; ++mi) {
    af[mi] = *(const bfrag8*)(Tp + (mi * 16 + cg) * 32 + rq * 8);
    int row = mi * 16 + cg;
    bfrag8 fI;
#pragma unroll
    for (int u = 0; u < 8; ++u) fI[u] = (row == rq * 8 + u) ? (short)0x3F80 : (short)0;
    afI[mi] = fI;
  }

  // ---- pass 1: row stats ----
  float s1[2][4] = {}, s2[2][4] = {}, a1[2][4] = {};
#pragma unroll 4
  for (int nj = 0; nj < 48; ++nj) {
    int h = nj * 16 + cg;
    bfrag8 vf = *(const bfrag8*)(vbase + h * 32 + rq * 8);
    bfrag8 qf = *(const bfrag8*)(qTa + (size_t)h * 32 + rq * 8);
    float gw = gwLds[h];
#pragma unroll
    for (int mi = 0; mi < 2; ++mi) {
      f32x4 zz = {0.f, 0.f, 0.f, 0.f};
      f32x4 p = __builtin_amdgcn_mfma_f32_16x16x32_bf16(af[mi], vf, zz, 0, 0, 0);
      f32x4 x4 = __builtin_amdgcn_mfma_f32_16x16x32_bf16(afI[mi], qf, p, 0, 0, 0);
#pragma unroll
      for (int r = 0; r < 4; ++r) {
        float x = x4[r];
        s1[mi][r] += x; s2[mi][r] += x * x; a1[mi][r] += x * gw;
      }
    }
  }
#pragma unroll
  for (int mi = 0; mi < 2; ++mi)
#pragma unroll
    for (int r = 0; r < 4; ++r) {
      s1[mi][r] = sum16(s1[mi][r]);
      s2[mi][r] = sum16(s2[mi][r]);
      a1[mi][r] = sum16(a1[mi][r]);
    }

  // ---- logits, softmax, u, c0 ----
  float uu[2][4], c0;
  {
    float mean[2][4], rstd[2][4], logit[2][4];
#pragma unroll
    for (int mi = 0; mi < 2; ++mi)
#pragma unroll
      for (int r = 0; r < 4; ++r) {
        float m1 = s1[mi][r] * (1.0f / 768.0f);
        float var = s2[mi][r] * (1.0f / 768.0f) - m1 * m1;
        float rs = rsqrtf(var + 1e-5f);
        mean[mi][r] = m1; rstd[mi][r] = rs;
        logit[mi][r] = rs * (a1[mi][r] - m1 * sgw_f) + sbw_f;
      }
    float mx = logit[0][0];
#pragma unroll
    for (int mi = 0; mi < 2; ++mi)
#pragma unroll
      for (int r = 0; r < 4; ++r) mx = fmaxf(mx, logit[mi][r]);
    mx = fmaxf(mx, __shfl_xor(mx, 16)); mx = fmaxf(mx, __shfl_xor(mx, 32));
    float se = 0.f, ee[2][4];
#pragma unroll
    for (int mi = 0; mi < 2; ++mi)
#pragma unroll
      for (int r = 0; r < 4; ++r) { ee[mi][r] = __expf(logit[mi][r] - mx); se += ee[mi][r]; }
    se += __shfl_xor(se, 16); se += __shfl_xor(se, 32);
    const float sinv = __builtin_amdgcn_rcpf(se);
    float c0a = 0.f;
#pragma unroll
    for (int mi = 0; mi < 2; ++mi)
#pragma unroll
      for (int r = 0; r < 4; ++r) {
        uu[mi][r] = ee[mi][r] * sinv * rstd[mi][r];
        c0a += uu[mi][r] * mean[mi][r];
      }
    c0a += __shfl_xor(c0a, 16); c0a += __shfl_xor(c0a, 32);
    c0 = c0a;
  }

  // ---- rank-1 staging: u (bf16) to LDS, then tv = u.T cooperatively ----
  if (cg == 0) {
#pragma unroll
    for (int mi = 0; mi < 2; ++mi)
#pragma unroll
      for (int r = 0; r < 4; ++r)
        uLds[pairIdx * 32 + mi * 16 + rq * 4 + r] = f2bf(uu[mi][r]);
  }
  __syncthreads();
  {
    const int j = l & 31, ihalf = l >> 5;
    float tvp = 0.f;
#pragma unroll
    for (int ii = 0; ii < 16; ++ii) {
      int i = ihalf * 16 + ii;
      tvp += bf2f(uLds[pairIdx * 32 + i]) * bf2f(Tp[i * 32 + j]);
    }
    tvp += __shfl_xor(tvp, 32);
    if (l < 32) tvLds[pairIdx * 32 + j] = f2bf(tvp);
  }
  __syncthreads();
  bfrag8 afT, afQ;
  {
    bfrag8 z8;
#pragma unroll
    for (int u = 0; u < 8; ++u) z8[u] = 0;
    afT = z8; afQ = z8;
    if (cg == 0) {
      afT = *(const bfrag8*)(tvLds + pairIdx * 32 + rq * 8);
      afQ = *(const bfrag8*)(uLds + pairIdx * 32 + rq * 8);
    }
  }

  // ---- pass 2 (rank-1): pooled[h] = tv.V[:,h] + u.q[:,h]; valid on rq==0 lanes ----
  float ps = 0.f, pq = 0.f, spc = 0.f;
#pragma unroll 4
  for (int nj = 0; nj < 48; ++nj) {
    int h = nj * 16 + cg;
    bfrag8 vf = *(const bfrag8*)(vbase + h * 32 + rq * 8);
    bfrag8 qf = *(const bfrag8*)(qTa + (size_t)h * 32 + rq * 8);
    f32x4 z1 = {0.f, 0.f, 0.f, 0.f};
    f32x4 z2 = {0.f, 0.f, 0.f, 0.f};
    f32x4 pv = __builtin_amdgcn_mfma_f32_16x16x32_bf16(afT, vf, z1, 0, 0, 0);
    f32x4 pu = __builtin_amdgcn_mfma_f32_16x16x32_bf16(afQ, qf, z2, 0, 0, 0);
    float x = pv[0] + pu[0];                       // row 0 of output = the rank-1 result
    float pooled = ln1_g[h] * (x - c0) + ln1_b[h];
    ps += pooled; pq += pooled * pooled;
    spc += pooled * gabLds[ah * 768 + h];
  }
  ps = sum16(ps); pq = sum16(pq); spc = sum16(spc);   // valid on rq==0 lanes (incl. lane 0)
  const float m2 = ps * (1.0f / 768.0f);
  const float var2 = pq * (1.0f / 768.0f) - m2 * m2;
  const float rs2 = rsqrtf(var2 + 1e-5f);
  const float* ea = entity_cls + (size_t)a_g * 768;
  const float* mb = mention_cls + (size_t)b_g * 768;
  float sg = 0.f;
#pragma unroll
  for (int u = 0; u < 12; ++u) sg += mb[l * 12 + u] * ea[l * 12 + u];
  sg = sum16(sg);
  sg += __shfl_xor(sg, 16); sg += __shfl_xor(sg, 32);
  float tot = rs2 * (spc - m2 * sga_f) + sba_f + sg;
  if (l == 0) out[b_g * 32 + a_g] = 0.5f * tot;
}

extern "C" void kernel_launch(void* const* d_in, const int* in_sizes, int n_in,
                              void* d_out, int out_size, void* d_ws, size_t ws_size,
                              hipStream_t stream) {
  const float* entity_cls     = (const float*)d_in[0];
  const float* entity_tokens  = (const float*)d_in[1];
  const float* mention_cls    = (const float*)d_in[2];
  const float* mention_tokens = (const float*)d_in[3];
  const float* Wq = (const float*)d_in[4];   const float* bq = (const float*)d_in[5];
  const float* Wk = (const float*)d_in[6];   const float* bk = (const float*)d_in[7];
  const float* Wv = (const float*)d_in[8];   const float* bv = (const float*)d_in[9];
  const float* ln1_g = (const float*)d_in[10]; const float* ln1_b = (const float*)d_in[11];
  const float* Wcls = (const float*)d_in[12];  const float* bcls = (const float*)d_in[13];
  const float* Wsp = (const float*)d_in[14];   const float* bsp = (const float*)d_in[15];
  const float* ln2_g = (const float*)d_in[16]; const float* ln2_b = (const float*)d_in[17];
  float* out = (float*)d_out;

  float* ws     = (float*)d_ws;
  float* ecls   = ws;                          // 32*768
  float* iq_sq  = ecls + 24576;                // 1024
  float* ik_sq  = iq_sq + 1024;                // 2048
  // (aux region retained for layout compatibility; unused now)
  unsigned short* qb = (unsigned short*)(ws + 55168);     // 1024*768
  unsigned short* qT = qb + 786432;                       // 32*768*32
  unsigned short* kb = qT + 786432;                       // 2048*768
  unsigned short* vT = kb + 1572864;                      // 64*768*32
  char* R = (char*)(vT + 1572864);
  unsigned short* Ae    = (unsigned short*)R;
  unsigned short* Am    = Ae + 786432;
  unsigned short* Acls  = Am + 1572864;
  unsigned short* WqT   = Acls + 24576;
  unsigned short* WkT   = WqT + 589824;
  unsigned short* WvT   = WkT + 589824;
  unsigned short* WclsT = WvT + 589824;

  prep_kernel<<<dim3(4635), dim3(256), 0, stream>>>(
      entity_tokens, mention_tokens, entity_cls, Ae, Am, Acls, iq_sq,
      Wq, Wk, Wv, Wcls, WqT, WkT, WvT, WclsT);
  proj_gemm_kernel<<<dim3(12, 16, 4), dim3(512), 0, stream>>>(
      Ae, Am, Acls, WqT, WkT, WvT, WclsT, bq, bk, bv, bcls,
      qb, qT, kb, vT, ecls, iq_sq, ik_sq);
  cos_attn_kernel<<<dim3(32, 8), dim3(512), 0, stream>>>(
      qb, kb, iq_sq, ik_sq, qT, vT,
      ln1_g, ln1_b, Wsp, bsp, ln2_g, ln2_b,
      ecls, entity_cls, mention_cls, out);
}

// Round 10
// 162.693 us; speedup vs baseline: 1.1613x; 1.0016x over previous
//
#include <hip/hip_runtime.h>
#include <math.h>

// Shapes (fixed): Na=32, La=32, B=64, Lb=32, Din=H=768.

typedef __attribute__((ext_vector_type(8))) short bfrag8;   // 8 bf16 in 4 VGPRs
typedef __attribute__((ext_vector_type(4))) float f32x4;

__device__ __forceinline__ unsigned short f2bf(float x) {
  union { float f; unsigned u; } v; v.f = x;
  unsigned r = v.u + 0x7fffu + ((v.u >> 16) & 1u);
  return (unsigned short)(r >> 16);
}
__device__ __forceinline__ float bf2f(unsigned short x) {
  union { float f; unsigned u; } v; v.u = ((unsigned)x) << 16; return v.f;
}

// DPP-based add-reduction over 16-lane rows (VALU pipe; avoids ds_swizzle latency).
template <int CTRL>
__device__ __forceinline__ float dpp_add(float x) {
  union { float f; int i; } a, b;
  a.f = x;
  b.i = __builtin_amdgcn_update_dpp(0, a.i, CTRL, 0xf, 0xf, true);
  return x + b.f;
}
// full sum over the 16 lanes of a DPP row (cg dimension), result in all 16 lanes
__device__ __forceinline__ float sum16(float x) {
  x = dpp_add<0xB1>(x);    // quad_perm [1,0,3,2]  : xor 1
  x = dpp_add<0x4E>(x);    // quad_perm [2,3,0,1]  : xor 2
  x = dpp_add<0x124>(x);   // row_ror:4
  x = dpp_add<0x128>(x);   // row_ror:8
  return x;
}

// ---------------- prep: casts (3 tensors) + zero norm buffer + 4 weight transposes -------------
__global__ __launch_bounds__(256) void prep_kernel(
    const float* __restrict__ a0, const float* __restrict__ a1, const float* __restrict__ a2,
    unsigned short* __restrict__ o0, unsigned short* __restrict__ o1, unsigned short* __restrict__ o2,
    float* __restrict__ nrm,
    const float* __restrict__ W0, const float* __restrict__ W1,
    const float* __restrict__ W2, const float* __restrict__ W3,
    unsigned short* __restrict__ T0, unsigned short* __restrict__ T1,
    unsigned short* __restrict__ T2, unsigned short* __restrict__ T3) {
  __shared__ float t[32][33];
  int bx = blockIdx.x;
  if (bx < 2331) {
    if (bx < 2328) {
      const float* in; unsigned short* out; int i, n4;
      if (bx < 768)       { in = a0; out = o0; i = bx * 256 + threadIdx.x;          n4 = 196608; }
      else if (bx < 2304) { in = a1; out = o1; i = (bx - 768) * 256 + threadIdx.x;  n4 = 393216; }
      else                { in = a2; out = o2; i = (bx - 2304) * 256 + threadIdx.x; n4 = 6144; }
      if (i >= n4) return;
      float4 f = ((const float4*)in)[i];
      ushort4 o;
      o.x = f2bf(f.x); o.y = f2bf(f.y); o.z = f2bf(f.z); o.w = f2bf(f.w);
      ((ushort4*)out)[i] = o;
    } else {
      int i = (bx - 2328) * 256 + threadIdx.x;
      if (i < 768) ((float4*)nrm)[i] = make_float4(0.f, 0.f, 0.f, 0.f);
    }
    return;
  }
  int idx = bx - 2331;
  int z = idx / 576, r2 = idx % 576;
  int tby = r2 / 24, tbx = r2 % 24;
  const float* W = (z == 0) ? W0 : (z == 1) ? W1 : (z == 2) ? W2 : W3;
  unsigned short* O = (z == 0) ? T0 : (z == 1) ? T1 : (z == 2) ? T2 : T3;
  const int gx = tbx * 32, gy = tby * 32;
  const int tx = threadIdx.x & 31, ty = threadIdx.x >> 5;
#pragma unroll
  for (int u = 0; u < 4; ++u) {
    int row = ty + u * 8;
    t[row][tx] = W[(size_t)(gy + row) * 768 + gx + tx];
  }
  __syncthreads();
#pragma unroll
  for (int u = 0; u < 4; ++u) {
    int row = ty + u * 8;
    O[(size_t)(gx + row) * 768 + gy + tx] = f2bf(t[tx][row]);
  }
}

// ---------------- projections, 128x64 tiles, 8 waves, ~2 blocks/CU ---------------------------
// z=0:q->qb+qT(+iq_sq), 1:k->kb(+ik_sq), 2:v->vT, 3:ecls
__global__ __launch_bounds__(512, 2) void proj_gemm_kernel(
    const unsigned short* __restrict__ Ae, const unsigned short* __restrict__ Am,
    const unsigned short* __restrict__ Acls,
    const unsigned short* __restrict__ WqT, const unsigned short* __restrict__ WkT,
    const unsigned short* __restrict__ WvT, const unsigned short* __restrict__ WclsT,
    const float* __restrict__ bq, const float* __restrict__ bk,
    const float* __restrict__ bv, const float* __restrict__ bcls,
    unsigned short* __restrict__ qb, unsigned short* __restrict__ qT,
    unsigned short* __restrict__ kb, unsigned short* __restrict__ vT,
    float* __restrict__ ecls, float* __restrict__ iq_sq, float* __restrict__ ik_sq) {
  const int z = blockIdx.z;
  const int M = (z == 0) ? 1024 : (z == 3) ? 32 : 2048;
  const int bm = blockIdx.y * 128;
  if (bm >= M) return;
  const unsigned short* A = (z == 3) ? Acls : (z == 0) ? Ae : Am;
  const unsigned short* B = (z == 0) ? WqT : (z == 1) ? WkT : (z == 2) ? WvT : WclsT;
  const float* bias = (z == 0) ? bq : (z == 1) ? bk : (z == 2) ? bv : bcls;

  __shared__ unsigned short As[128 * 64];
  __shared__ unsigned short Bs[64 * 64];
  const int t = threadIdx.x;
  const int bn = blockIdx.x * 64;
  const int l = t & 63, w = t >> 6;        // 8 waves
  const int wm = w & 3, wn = w >> 2;       // 4 row strips (32) x 2 col strips (32)
  const int cg = l & 15, rq = l >> 4;

  f32x4 acc[2][2];
#pragma unroll
  for (int mi = 0; mi < 2; ++mi)
#pragma unroll
    for (int nj = 0; nj < 2; ++nj) { f32x4 zz = {0.f, 0.f, 0.f, 0.f}; acc[mi][nj] = zz; }

  for (int k0 = 0; k0 < 768; k0 += 64) {
    __syncthreads();
#pragma unroll
    for (int u = 0; u < 2; ++u) {
      int c = t + u * 512;
      int row = c >> 3, kc = c & 7;
      int gm = bm + row; gm = gm < M ? gm : M - 1;
      int4 av = *(const int4*)(A + (size_t)gm * 768 + k0 + kc * 8);
      *(int4*)(As + row * 64 + ((kc ^ (row & 7)) * 8)) = av;
    }
    {
      int row = t >> 3, kc = t & 7;
      int4 bv4 = *(const int4*)(B + (size_t)(bn + row) * 768 + k0 + kc * 8);
      *(int4*)(Bs + row * 64 + ((kc ^ (row & 7)) * 8)) = bv4;
    }
    __syncthreads();
#pragma unroll
    for (int kk = 0; kk < 2; ++kk) {
      bfrag8 af[2], bf[2];
      const int kc = kk * 4 + rq;
#pragma unroll
      for (int mi = 0; mi < 2; ++mi) {
        int arow = wm * 32 + mi * 16 + cg;
        af[mi] = *(const bfrag8*)(As + arow * 64 + ((kc ^ (arow & 7)) * 8));
      }
#pragma unroll
      for (int nj = 0; nj < 2; ++nj) {
        int brow = wn * 32 + nj * 16 + cg;
        bf[nj] = *(const bfrag8*)(Bs + brow * 64 + ((kc ^ (brow & 7)) * 8));
      }
#pragma unroll
      for (int mi = 0; mi < 2; ++mi)
#pragma unroll
        for (int nj = 0; nj < 2; ++nj)
          acc[mi][nj] = __builtin_amdgcn_mfma_f32_16x16x32_bf16(af[mi], bf[nj], acc[mi][nj], 0, 0, 0);
    }
  }

  float p[2][4] = {};
#pragma unroll
  for (int mi = 0; mi < 2; ++mi) {
#pragma unroll
    for (int nj = 0; nj < 2; ++nj) {
      int gn = bn + wn * 32 + nj * 16 + cg;
      float bs = bias[gn];
#pragma unroll
      for (int r = 0; r < 4; ++r) {
        int gm = bm + wm * 32 + mi * 16 + rq * 4 + r;
        if (gm >= M) continue;
        float val = acc[mi][nj][r] + bs;
        if (z < 2) p[mi][r] += val * val;
        unsigned short bfv = f2bf(val);
        if (z == 0) {
          qb[(size_t)gm * 768 + gn] = bfv;
          int at = gm >> 5, j = gm & 31;
          qT[((size_t)at * 768 + gn) * 32 + j] = bfv;
        } else if (z == 1) kb[(size_t)gm * 768 + gn] = bfv;
        else if (z == 2) {
          int bb = gm >> 5, j = gm & 31;
          vT[((size_t)bb * 768 + gn) * 32 + j] = bfv;
        } else ecls[(size_t)gm * 768 + gn] = val;
      }
    }
  }
  if (z < 2) {
    float* nrm = (z == 0) ? iq_sq : ik_sq;
#pragma unroll
    for (int mi = 0; mi < 2; ++mi)
#pragma unroll
      for (int r = 0; r < 4; ++r) {
        float s = sum16(p[mi][r]);
        if (cg == 0) {
          int gm = bm + wm * 32 + mi * 16 + rq * 4 + r;
          atomicAdd(&nrm[gm], s);
        }
      }
  }
}

// ---------------- fused cos_sink + attn: one b per block, 4 waves, 1 pair/wave ---------------
// grid (64, 8): x = b, y = a-group (bm = y*128). 512 blocks, ~72 KB LDS -> 2 blocks/CU.
// Cross-block phase overlap: when one block barriers/serial-Sinkhorns, the co-resident
// block's waves keep the SIMDs busy. Wave w = a_local; full 32x32 pair per wave (R3 math).
__global__ __launch_bounds__(256, 4) void cos_attn_kernel(
    const unsigned short* __restrict__ qb, const unsigned short* __restrict__ kb,
    const float* __restrict__ iq_sq, const float* __restrict__ ik_sq,
    const unsigned short* __restrict__ qT,  // [32][768][32]
    const unsigned short* __restrict__ vT,  // [64][768][32]
    const float* __restrict__ ln1_g, const float* __restrict__ ln1_b,
    const float* __restrict__ Wsp, const float* __restrict__ bsp,
    const float* __restrict__ ln2_g, const float* __restrict__ ln2_b,
    const float* __restrict__ ecls,
    const float* __restrict__ entity_cls, const float* __restrict__ mention_cls,
    float* __restrict__ out) {
  __shared__ unsigned short vLds[768 * 32];                // 48 KB  [h][lb] this block's b
  __shared__ __align__(16) unsigned short scratch[10240];  // 20 KB: As(16K)+Bs(4K); Tlds(8K) aliases
  __shared__ float gwLds[768];                             // 3 KB   ln1_g*Wsp
  __shared__ float ldsIq[128], ldsIk[32];
  __shared__ float red[40];                                // 4 waves x 10 coefficient partials
  __shared__ __align__(16) unsigned short uLds[4 * 32];    // u (bf16) per pair
  __shared__ __align__(16) unsigned short tvLds[4 * 32];   // tv = u.T (bf16) per pair

  unsigned short* As = scratch;              // [128*64]
  unsigned short* Bs = scratch + 8192;       // [32*64]
  unsigned short* Tlds = scratch;            // [4 pairs][32][32], alive after GEMM only

  const int t = threadIdx.x;
  const int l = t & 63, w = t >> 6;          // 4 waves; w = a_local = pair index
  const int bm = blockIdx.y * 128;
  const int b_g = blockIdx.x;
  const int cg = l & 15, rq = l >> 4;

  // ---- phase 0: per-block coefficient partials (visibility via first k-loop barrier) ----
  {
    float sgw = 0.f, sbw = 0.f, sga[4] = {}, sba[4] = {};
    for (int h = t; h < 768; h += 256) {
      float g1 = ln1_g[h], b1 = ln1_b[h], wsp = Wsp[h];
      float g2 = ln2_g[h], b2 = ln2_b[h];
      float gw = g1 * wsp;
      gwLds[h] = gw;
      sgw += gw; sbw += b1 * wsp;
#pragma unroll
      for (int aa = 0; aa < 4; ++aa) {
        float ec = ecls[(size_t)((blockIdx.y << 2) + aa) * 768 + h];
        sga[aa] += g2 * ec; sba[aa] += b2 * ec;
      }
    }
    sgw = sum16(sgw); sbw = sum16(sbw);
#pragma unroll
    for (int aa = 0; aa < 4; ++aa) { sga[aa] = sum16(sga[aa]); sba[aa] = sum16(sba[aa]); }
#pragma unroll
    for (int m = 16; m < 64; m <<= 1) {
      sgw += __shfl_xor(sgw, m); sbw += __shfl_xor(sbw, m);
#pragma unroll
      for (int aa = 0; aa < 4; ++aa) { sga[aa] += __shfl_xor(sga[aa], m); sba[aa] += __shfl_xor(sba[aa], m); }
    }
    if (l == 0) {
      red[w * 10 + 0] = sgw; red[w * 10 + 1] = sbw;
#pragma unroll
      for (int aa = 0; aa < 4; ++aa) { red[w * 10 + 2 + aa] = sga[aa]; red[w * 10 + 6 + aa] = sba[aa]; }
    }
  }
  if (t < 128) ldsIq[t] = iq_sq[bm + t];
  else if (t < 160) ldsIk[t - 128] = ik_sq[b_g * 32 + (t - 128)];

  // ---- phase 1: cos GEMM (32x32 per wave) + vT->LDS copy interleaved ----
  const int4* vsrc = (const int4*)(vT + (size_t)b_g * 768 * 32);
  int4* vdst = (int4*)vLds;

  f32x4 acc[2][2];
#pragma unroll
  for (int mi = 0; mi < 2; ++mi)
#pragma unroll
    for (int nj = 0; nj < 2; ++nj) { f32x4 zz = {0.f, 0.f, 0.f, 0.f}; acc[mi][nj] = zz; }

  for (int k0 = 0, s = 0; k0 < 768; k0 += 64, ++s) {
    __syncthreads();
#pragma unroll
    for (int u = 0; u < 4; ++u) {
      int c = t + u * 256;
      int row = c >> 3, kc = c & 7;
      int4 av = *(const int4*)(qb + (size_t)(bm + row) * 768 + k0 + kc * 8);
      *(int4*)(As + row * 64 + ((kc ^ (row & 7)) * 8)) = av;
    }
    {
      int row = t >> 3, kc = t & 7;   // rows 0..31
      int4 bv4 = *(const int4*)(kb + (size_t)(b_g * 32 + row) * 768 + k0 + kc * 8);
      *(int4*)(Bs + row * 64 + ((kc ^ (row & 7)) * 8)) = bv4;
    }
    vdst[t + s * 256] = vsrc[t + s * 256];
    __syncthreads();
#pragma unroll
    for (int kk = 0; kk < 2; ++kk) {
      bfrag8 af[2], bf[2];
      const int kc = kk * 4 + rq;
#pragma unroll
      for (int mi = 0; mi < 2; ++mi) {
        int arow = w * 32 + mi * 16 + cg;
        af[mi] = *(const bfrag8*)(As + arow * 64 + ((kc ^ (arow & 7)) * 8));
      }
#pragma unroll
      for (int nj = 0; nj < 2; ++nj) {
        int brow = nj * 16 + cg;
        bf[nj] = *(const bfrag8*)(Bs + brow * 64 + ((kc ^ (brow & 7)) * 8));
      }
#pragma unroll
      for (int mi = 0; mi < 2; ++mi)
#pragma unroll
        for (int nj = 0; nj < 2; ++nj)
          acc[mi][nj] = __builtin_amdgcn_mfma_f32_16x16x32_bf16(af[mi], bf[nj], acc[mi][nj], 0, 0, 0);
    }
  }

  // ---- phase 2: cosine normalize, exp, Sinkhorn, L2-row-normalize (one 32x32 pair) ----
  float irow[2][4], icol[2];
#pragma unroll
  for (int mi = 0; mi < 2; ++mi)
#pragma unroll
    for (int r = 0; r < 4; ++r) {
      float sv = ldsIq[w * 32 + mi * 16 + rq * 4 + r];
      irow[mi][r] = 1.0f / fmaxf(sqrtf(sv), 1e-8f);
    }
#pragma unroll
  for (int nj = 0; nj < 2; ++nj) {
    float sv = ldsIk[nj * 16 + cg];
    icol[nj] = 1.0f / fmaxf(sqrtf(sv), 1e-8f);
  }
#pragma unroll
  for (int mi = 0; mi < 2; ++mi)
#pragma unroll
    for (int nj = 0; nj < 2; ++nj)
#pragma unroll
      for (int r = 0; r < 4; ++r)
        acc[mi][nj][r] = __expf(acc[mi][nj][r] * irow[mi][r] * icol[nj] * 10.0f);

  for (int it = 0; it < 10; ++it) {
#pragma unroll
    for (int mi = 0; mi < 2; ++mi)
#pragma unroll
      for (int r = 0; r < 4; ++r) {
        float rs = sum16(acc[mi][0][r] + acc[mi][1][r]);
        float rinv = __builtin_amdgcn_rcpf(rs);
        acc[mi][0][r] *= rinv; acc[mi][1][r] *= rinv;
      }
#pragma unroll
    for (int nj = 0; nj < 2; ++nj) {
      float cs = acc[0][nj][0] + acc[0][nj][1] + acc[0][nj][2] + acc[0][nj][3]
               + acc[1][nj][0] + acc[1][nj][1] + acc[1][nj][2] + acc[1][nj][3];
      cs += __shfl_xor(cs, 16); cs += __shfl_xor(cs, 32);
      float cinv = __builtin_amdgcn_rcpf(cs);
#pragma unroll
      for (int mi = 0; mi < 2; ++mi)
#pragma unroll
        for (int r = 0; r < 4; ++r) acc[mi][nj][r] *= cinv;
    }
  }

#pragma unroll
  for (int mi = 0; mi < 2; ++mi)
#pragma unroll
    for (int r = 0; r < 4; ++r) {
      float ss = sum16(acc[mi][0][r] * acc[mi][0][r] + acc[mi][1][r] * acc[mi][1][r]);
      float tinv = 1.0f / fmaxf(sqrtf(ss), 1e-12f);
      acc[mi][0][r] *= tinv; acc[mi][1][r] *= tinv;
    }

  // ---- phase 3: T -> LDS (aliases dead As/Bs; barrier on both sides) ----
  __syncthreads();   // all waves past their last As/Bs fragment read
  {
    unsigned short* base = Tlds + (w << 10);
#pragma unroll
    for (int mi = 0; mi < 2; ++mi)
#pragma unroll
      for (int nj = 0; nj < 2; ++nj)
#pragma unroll
        for (int r = 0; r < 4; ++r)
          base[(mi * 16 + rq * 4 + r) * 32 + nj * 16 + cg] = f2bf(acc[mi][nj][r]);
  }
  __syncthreads();   // Tlds + vLds ready

  // ---- phase 4: attention. wave w = a_local; b shared by block ----
  const int a_g = (blockIdx.y << 2) + w;

  float sgw_f = 0.f, sbw_f = 0.f, sga_f = 0.f, sba_f = 0.f;
#pragma unroll
  for (int wv = 0; wv < 4; ++wv) {
    sgw_f += red[wv * 10 + 0]; sbw_f += red[wv * 10 + 1];
    sga_f += red[wv * 10 + 2 + w]; sba_f += red[wv * 10 + 6 + w];
  }
  sbw_f += bsp[0];

  const unsigned short* qTa = qT + (size_t)a_g * 24576;
  const unsigned short* Tp = Tlds + (w << 10);
  bfrag8 af[2], afI[2];
#pragma unroll
  for (int mi = 0; mi < 2; ++mi) {
    af[mi] = *(const bfrag8*)(Tp + (mi * 16 + cg) * 32 + rq * 8);
    int row = mi * 16 + cg;
    bfrag8 fI;
#pragma unroll
    for (int u = 0; u < 8; ++u) fI[u] = (row == rq * 8 + u) ? (short)0x3F80 : (short)0;
    afI[mi] = fI;
  }

  // ---- pass 1: row stats ----
  float s1[2][4] = {}, s2[2][4] = {}, a1[2][4] = {};
#pragma unroll 4
  for (int nj = 0; nj < 48; ++nj) {
    int h = nj * 16 + cg;
    bfrag8 vf = *(const bfrag8*)(vLds + h * 32 + rq * 8);
    bfrag8 qf = *(const bfrag8*)(qTa + (size_t)h * 32 + rq * 8);
    float gw = gwLds[h];
#pragma unroll
    for (int mi = 0; mi < 2; ++mi) {
      f32x4 zz = {0.f, 0.f, 0.f, 0.f};
      f32x4 p = __builtin_amdgcn_mfma_f32_16x16x32_bf16(af[mi], vf, zz, 0, 0, 0);
      f32x4 x4 = __builtin_amdgcn_mfma_f32_16x16x32_bf16(afI[mi], qf, p, 0, 0, 0);
#pragma unroll
      for (int r = 0; r < 4; ++r) {
        float x = x4[r];
        s1[mi][r] += x; s2[mi][r] += x * x; a1[mi][r] += x * gw;
      }
    }
  }
#pragma unroll
  for (int mi = 0; mi < 2; ++mi)
#pragma unroll
    for (int r = 0; r < 4; ++r) {
      s1[mi][r] = sum16(s1[mi][r]);
      s2[mi][r] = sum16(s2[mi][r]);
      a1[mi][r] = sum16(a1[mi][r]);
    }

  // ---- logits, softmax, u, c0 ----
  float uu[2][4], c0;
  {
    float mean[2][4], rstd[2][4], logit[2][4];
#pragma unroll
    for (int mi = 0; mi < 2; ++mi)
#pragma unroll
      for (int r = 0; r < 4; ++r) {
        float m1 = s1[mi][r] * (1.0f / 768.0f);
        float var = s2[mi][r] * (1.0f / 768.0f) - m1 * m1;
        float rs = rsqrtf(var + 1e-5f);
        mean[mi][r] = m1; rstd[mi][r] = rs;
        logit[mi][r] = rs * (a1[mi][r] - m1 * sgw_f) + sbw_f;
      }
    float mx = logit[0][0];
#pragma unroll
    for (int mi = 0; mi < 2; ++mi)
#pragma unroll
      for (int r = 0; r < 4; ++r) mx = fmaxf(mx, logit[mi][r]);
    mx = fmaxf(mx, __shfl_xor(mx, 16)); mx = fmaxf(mx, __shfl_xor(mx, 32));
    float se = 0.f, ee[2][4];
#pragma unroll
    for (int mi = 0; mi < 2; ++mi)
#pragma unroll
      for (int r = 0; r < 4; ++r) { ee[mi][r] = __expf(logit[mi][r] - mx); se += ee[mi][r]; }
    se += __shfl_xor(se, 16); se += __shfl_xor(se, 32);
    const float sinv = __builtin_amdgcn_rcpf(se);
    float c0a = 0.f;
#pragma unroll
    for (int mi = 0; mi < 2; ++mi)
#pragma unroll
      for (int r = 0; r < 4; ++r) {
        uu[mi][r] = ee[mi][r] * sinv * rstd[mi][r];
        c0a += uu[mi][r] * mean[mi][r];
      }
    c0a += __shfl_xor(c0a, 16); c0a += __shfl_xor(c0a, 32);
    c0 = c0a;
  }

  // ---- rank-1 staging: u (bf16) to LDS, then tv = u.T cooperatively ----
  if (cg == 0) {
#pragma unroll
    for (int mi = 0; mi < 2; ++mi)
#pragma unroll
      for (int r = 0; r < 4; ++r)
        uLds[w * 32 + mi * 16 + rq * 4 + r] = f2bf(uu[mi][r]);
  }
  __syncthreads();
  {
    const int j = l & 31, ihalf = l >> 5;
    float tvp = 0.f;
#pragma unroll
    for (int ii = 0; ii < 16; ++ii) {
      int i = ihalf * 16 + ii;
      tvp += bf2f(uLds[w * 32 + i]) * bf2f(Tp[i * 32 + j]);
    }
    tvp += __shfl_xor(tvp, 32);
    if (l < 32) tvLds[w * 32 + j] = f2bf(tvp);
  }
  __syncthreads();
  bfrag8 afT, afQ;
  {
    bfrag8 z8;
#pragma unroll
    for (int u = 0; u < 8; ++u) z8[u] = 0;
    afT = z8; afQ = z8;
    if (cg == 0) {
      afT = *(const bfrag8*)(tvLds + w * 32 + rq * 8);
      afQ = *(const bfrag8*)(uLds + w * 32 + rq * 8);
    }
  }

  // ---- pass 2 (rank-1): pooled[h] = tv.V[:,h] + u.q[:,h]; valid on rq==0 lanes ----
  const float* eca = ecls + (size_t)a_g * 768;
  float ps = 0.f, pq = 0.f, spc = 0.f;
#pragma unroll 4
  for (int nj = 0; nj < 48; ++nj) {
    int h = nj * 16 + cg;
    bfrag8 vf = *(const bfrag8*)(vLds + h * 32 + rq * 8);
    bfrag8 qf = *(const bfrag8*)(qTa + (size_t)h * 32 + rq * 8);
    f32x4 z1 = {0.f, 0.f, 0.f, 0.f};
    f32x4 z2 = {0.f, 0.f, 0.f, 0.f};
    f32x4 pv = __builtin_amdgcn_mfma_f32_16x16x32_bf16(afT, vf, z1, 0, 0, 0);
    f32x4 pu = __builtin_amdgcn_mfma_f32_16x16x32_bf16(afQ, qf, z2, 0, 0, 0);
    float x = pv[0] + pu[0];                       // row 0 of output = the rank-1 result
    float pooled = ln1_g[h] * (x - c0) + ln1_b[h];
    ps += pooled; pq += pooled * pooled;
    spc += pooled * (ln2_g[h] * eca[h]);
  }
  ps = sum16(ps); pq = sum16(pq); spc = sum16(spc);   // valid on rq==0 lanes (incl. lane 0)
  const float m2 = ps * (1.0f / 768.0f);
  const float var2 = pq * (1.0f / 768.0f) - m2 * m2;
  const float rs2 = rsqrtf(var2 + 1e-5f);
  const float* ea = entity_cls + (size_t)a_g * 768;
  const float* mb = mention_cls + (size_t)b_g * 768;
  float sg = 0.f;
#pragma unroll
  for (int u = 0; u < 12; ++u) sg += mb[l * 12 + u] * ea[l * 12 + u];
  sg = sum16(sg);
  sg += __shfl_xor(sg, 16); sg += __shfl_xor(sg, 32);
  float tot = rs2 * (spc - m2 * sga_f) + sba_f + sg;
  if (l == 0) out[b_g * 32 + a_g] = 0.5f * tot;
}

extern "C" void kernel_launch(void* const* d_in, const int* in_sizes, int n_in,
                              void* d_out, int out_size, void* d_ws, size_t ws_size,
                              hipStream_t stream) {
  const float* entity_cls     = (const float*)d_in[0];
  const float* entity_tokens  = (const float*)d_in[1];
  const float* mention_cls    = (const float*)d_in[2];
  const float* mention_tokens = (const float*)d_in[3];
  const float* Wq = (const float*)d_in[4];   const float* bq = (const float*)d_in[5];
  const float* Wk = (const float*)d_in[6];   const float* bk = (const float*)d_in[7];
  const float* Wv = (const float*)d_in[8];   const float* bv = (const float*)d_in[9];
  const float* ln1_g = (const float*)d_in[10]; const float* ln1_b = (const float*)d_in[11];
  const float* Wcls = (const float*)d_in[12];  const float* bcls = (const float*)d_in[13];
  const float* Wsp = (const float*)d_in[14];   const float* bsp = (const float*)d_in[15];
  const float* ln2_g = (const float*)d_in[16]; const float* ln2_b = (const float*)d_in[17];
  float* out = (float*)d_out;

  float* ws     = (float*)d_ws;
  float* ecls   = ws;                          // 32*768
  float* iq_sq  = ecls + 24576;                // 1024
  float* ik_sq  = iq_sq + 1024;                // 2048
  // (aux region retained for layout compatibility; unused now)
  unsigned short* qb = (unsigned short*)(ws + 55168);     // 1024*768
  unsigned short* qT = qb + 786432;                       // 32*768*32
  unsigned short* kb = qT + 786432;                       // 2048*768
  unsigned short* vT = kb + 1572864;                      // 64*768*32
  char* R = (char*)(vT + 1572864);
  unsigned short* Ae    = (unsigned short*)R;
  unsigned short* Am    = Ae + 786432;
  unsigned short* Acls  = Am + 1572864;
  unsigned short* WqT   = Acls + 24576;
  unsigned short* WkT   = WqT + 589824;
  unsigned short* WvT   = WkT + 589824;
  unsigned short* WclsT = WvT + 589824;

  prep_kernel<<<dim3(4635), dim3(256), 0, stream>>>(
      entity_tokens, mention_tokens, entity_cls, Ae, Am, Acls, iq_sq,
      Wq, Wk, Wv, Wcls, WqT, WkT, WvT, WclsT);
  proj_gemm_kernel<<<dim3(12, 16, 4), dim3(512), 0, stream>>>(
      Ae, Am, Acls, WqT, WkT, WvT, WclsT, bq, bk, bv, bcls,
      qb, qT, kb, vT, ecls, iq_sq, ik_sq);
  cos_attn_kernel<<<dim3(64, 8), dim3(256), 0, stream>>>(
      qb, kb, iq_sq, ik_sq, qT, vT,
      ln1_g, ln1_b, Wsp, bsp, ln2_g, ln2_b,
      ecls, entity_cls, mention_cls, out);
}